// Round 1
// baseline (570.827 us; speedup 1.0000x reference)
//
#include <hip/hip_runtime.h>
#include <math.h>

#define BB 256
#define SS 64
#define DIMM 1024
#define NHH 8
#define DHH 128

__device__ __forceinline__ float logsigf(float x) {
    return fminf(x, 0.0f) - log1pf(__expf(-fabsf(x)));
}

// Kernel 1: fused gate GEMM + log-sigmoid + cumsum + prefix-max.
// One block per batch b (64 rows = all s). Wave w owns K-slice [w*768, w*768+768).
// K-slice index made wave-uniform via readfirstlane so weight reads become scalar loads.
__global__ __launch_bounds__(256) void k_gates(
    const float* __restrict__ q, const float* __restrict__ k, const float* __restrict__ v,
    const float* __restrict__ igw, const float* __restrict__ igb,
    const float* __restrict__ fgw, const float* __restrict__ fgb,
    float* __restrict__ ig_ws, float* __restrict__ csum_ws, float* __restrict__ pmax_ws)
{
    const int b = blockIdx.x;
    const int t = threadIdx.x;
    const int s = t & 63;
    const int ksl = __builtin_amdgcn_readfirstlane(t >> 6);
    const int rowbase = (b * SS + s) * DIMM;

    float accI[8] = {0,0,0,0,0,0,0,0};
    float accF[8] = {0,0,0,0,0,0,0,0};
    const int pbase = ksl * 768;
    #pragma unroll 4
    for (int it = 0; it < 192; ++it) {
        const int p = pbase + it * 4;
        const float* src;
        if (p < DIMM)        src = q + rowbase + p;
        else if (p < 2*DIMM) src = k + rowbase + (p - DIMM);
        else                 src = v + rowbase + (p - 2*DIMM);
        const float4 x = *reinterpret_cast<const float4*>(src);
        #pragma unroll
        for (int h = 0; h < 8; ++h) {
            const float* wi = igw + h * 3072 + p;
            const float* wf = fgw + h * 3072 + p;
            accI[h] = fmaf(x.x, wi[0], fmaf(x.y, wi[1], fmaf(x.z, wi[2], fmaf(x.w, wi[3], accI[h]))));
            accF[h] = fmaf(x.x, wf[0], fmaf(x.y, wf[1], fmaf(x.z, wf[2], fmaf(x.w, wf[3], accF[h]))));
        }
    }
    __shared__ float red[4][64][17];
    #pragma unroll
    for (int g = 0; g < 8; ++g) { red[ksl][s][g] = accI[g]; red[ksl][s][g+8] = accF[g]; }
    __syncthreads();
    if (t < 64) {
        #pragma unroll
        for (int h = 0; h < 8; ++h) {
            float ig = red[0][s][h]   + red[1][s][h]   + red[2][s][h]   + red[3][s][h]   + igb[h];
            float fg = red[0][s][h+8] + red[1][s][h+8] + red[2][s][h+8] + red[3][s][h+8] + fgb[h];
            float lf = logsigf(fg);
            // inclusive scan of lf over the 64 lanes
            float cs = lf;
            #pragma unroll
            for (int d = 1; d < 64; d <<= 1) {
                float o = __shfl_up(cs, (unsigned)d, 64);
                if (s >= d) cs += o;
            }
            // prefix-max of (ig[j] - csum[j+1]) -> row max of log_D is csum[i+1] + pmax[i]
            float pm = ig - cs;
            #pragma unroll
            for (int d = 1; d < 64; d <<= 1) {
                float o = __shfl_up(pm, (unsigned)d, 64);
                if (s >= d) pm = fmaxf(pm, o);
            }
            const int base = b * NHH + h;
            ig_ws[base * SS + s] = ig;
            csum_ws[base * 65 + s + 1] = cs;
            if (s == 0) csum_ws[base * 65] = 0.0f;
            pmax_ws[base * SS + s] = pm;
        }
    }
}

// Kernel 2: khop[b][h][v][m] = dot(q[b,v,h*DH:...], rpe[hops[v,m], h*DH:...]) for m <= v.
// Block = (v, h); thread t = batch b; PE staged transposed in LDS (broadcast reads).
__global__ __launch_bounds__(256) void k_khop(
    const float* __restrict__ q, const float* __restrict__ rpe, const int* __restrict__ hops,
    float* __restrict__ khop_ws)
{
    const int v = blockIdx.x;
    const int h = blockIdx.y;
    const int t = threadIdx.x;          // = b
    __shared__ float peT[DHH][68];      // [c][m], padded
    const int mcnt = v + 1;
    for (int idx = t; idx < mcnt * DHH; idx += 256) {
        const int m = idx >> 7;
        const int c = idx & 127;
        peT[c][m] = rpe[hops[v * SS + m] * DIMM + h * DHH + c];
    }
    float4 qr[32];
    const float4* qp = reinterpret_cast<const float4*>(q + (t * SS + v) * DIMM + h * DHH);
    #pragma unroll
    for (int e = 0; e < 32; ++e) qr[e] = qp[e];
    __syncthreads();
    float* outp = khop_ws + ((t * NHH + h) * SS + v) * SS;
    for (int m4 = 0; m4 * 4 <= v; ++m4) {
        float ax = 0.f, ay = 0.f, az = 0.f, aw = 0.f;
        #pragma unroll
        for (int e = 0; e < 32; ++e) {
            #pragma unroll
            for (int cc = 0; cc < 4; ++cc) {
                const float fv = (cc == 0) ? qr[e].x : (cc == 1) ? qr[e].y : (cc == 2) ? qr[e].z : qr[e].w;
                const float4 p4 = *reinterpret_cast<const float4*>(&peT[e * 4 + cc][m4 * 4]);
                ax = fmaf(fv, p4.x, ax); ay = fmaf(fv, p4.y, ay);
                az = fmaf(fv, p4.z, az); aw = fmaf(fv, p4.w, aw);
            }
        }
        const int m0 = m4 * 4;
        if (m0 + 3 <= v) *reinterpret_cast<float4*>(outp + m0) = make_float4(ax, ay, az, aw);
        else {
            outp[m0] = ax;
            if (m0 + 1 <= v) outp[m0 + 1] = ay;
            if (m0 + 2 <= v) outp[m0 + 2] = az;
        }
    }
}

// Kernel 3: per (b,h): C = (QK^T + khop) * D, normalize, PV, fused per-head LayerNorm.
__global__ __launch_bounds__(256) void k_attn(
    const float* __restrict__ q, const float* __restrict__ k, const float* __restrict__ v,
    const float* __restrict__ lnw, const float* __restrict__ lnb,
    const float* __restrict__ ig_ws, const float* __restrict__ csum_ws,
    const float* __restrict__ pmax_ws, const float* __restrict__ khop_ws,
    float* __restrict__ out)
{
    const int bid = blockIdx.x;
    const int b = bid >> 3, h = bid & 7;
    const int t = threadIdx.x;
    __shared__ float ks2[SS][4][36];    // K tile in 32-wide column slices (conflict-free b128)
    __shared__ float cs[SS][68];        // khop preload, overwritten in place by C
    __shared__ float csum_s[65];
    __shared__ float ig_s[64];
    __shared__ float pmax_s[64];
    __shared__ float invr[64];
    const float rs_dh = 0.08838834764831845f;  // 1/sqrt(128)

    // --- stage K (scaled), khop, gate vectors ---
    for (int idx = t; idx < SS * 32; idx += 256) {
        const int row = idx >> 5, c4 = idx & 31;
        float4 kv = *reinterpret_cast<const float4*>(k + ((b * SS + row) * DIMM + h * DHH + c4 * 4));
        kv.x *= rs_dh; kv.y *= rs_dh; kv.z *= rs_dh; kv.w *= rs_dh;
        *reinterpret_cast<float4*>(&ks2[row][c4 >> 3][(c4 & 7) * 4]) = kv;
    }
    const float* khb = khop_ws + (b * NHH + h) * SS * SS;
    for (int idx = t; idx < SS * 16; idx += 256) {
        const int row = idx >> 4, j4 = idx & 15;
        *reinterpret_cast<float4*>(&cs[row][j4 * 4]) =
            *reinterpret_cast<const float4*>(khb + row * SS + j4 * 4);
    }
    const int cb = b * NHH + h;
    if (t < 65) csum_s[t] = csum_ws[cb * 65 + t];
    if (t >= 128 && t < 192) ig_s[t - 128] = ig_ws[cb * SS + (t - 128)];
    if (t >= 192) pmax_s[t - 192] = pmax_ws[cb * SS + (t - 192)];

    const int i = t >> 2, qq = t & 3;   // quad-per-row; qq owns a 32-wide c-slice
    float4 qr[8];
    {
        const float4* qp = reinterpret_cast<const float4*>(q + ((b * SS + i) * DIMM + h * DHH + qq * 32));
        #pragma unroll
        for (int e = 0; e < 8; ++e) qr[e] = qp[e];
    }
    __syncthreads();

    // --- C phase: lower-triangular (qk + khop) * exp(logD - m_i) ---
    const float m_i = csum_s[i + 1] + pmax_s[i];
    float rs = 0.0f;
    for (int j = 0; j <= i; ++j) {
        float part = 0.0f;
        #pragma unroll
        for (int e = 0; e < 8; ++e) {
            const float4 kk = *reinterpret_cast<const float4*>(&ks2[j][qq][e * 4]);
            part = fmaf(qr[e].x, kk.x, part); part = fmaf(qr[e].y, kk.y, part);
            part = fmaf(qr[e].z, kk.z, part); part = fmaf(qr[e].w, kk.w, part);
        }
        part += __shfl_xor(part, 1, 64);
        part += __shfl_xor(part, 2, 64);
        if ((j & 3) == qq) {                 // finalize lane for this j
            const float sc = part + cs[i][j];
            const float logD = csum_s[i + 1] - csum_s[j + 1] + ig_s[j];
            const float C = sc * __expf(logD - m_i);
            rs += C;
            cs[i][j] = C;
        }
    }
    // zero the upper triangle of this row (my residue class)
    for (int j = i + 1 + ((qq - (i + 1)) & 3); j < SS; j += 4) cs[i][j] = 0.0f;
    rs += __shfl_xor(rs, 1, 64);
    rs += __shfl_xor(rs, 2, 64);
    const float nrm = fmaxf(fabsf(rs), __expf(-m_i));
    if (qq == 0) invr[i] = 1.0f / (nrm + 1e-6f);
    __syncthreads();

    // --- PV: h[i][c] = sum_j C[i][j] * v[j][c]; thread = (row-group g, column c) ---
    const int g = t >> 7, c = t & 127;
    float acc[32];
    #pragma unroll
    for (int r = 0; r < 32; ++r) acc[r] = 0.0f;
    const int j4max = (g == 0) ? 8 : 16;     // rows 0..31 only need j<32
    const float* vb = v + (b * SS) * DIMM + h * DHH + c;
    for (int j4 = 0; j4 < j4max; ++j4) {
        const float v0 = vb[(j4 * 4 + 0) * DIMM];
        const float v1 = vb[(j4 * 4 + 1) * DIMM];
        const float v2 = vb[(j4 * 4 + 2) * DIMM];
        const float v3 = vb[(j4 * 4 + 3) * DIMM];
        #pragma unroll
        for (int r = 0; r < 32; ++r) {
            const float4 cw = *reinterpret_cast<const float4*>(&cs[g * 32 + r][j4 * 4]);
            acc[r] = fmaf(cw.x, v0, fmaf(cw.y, v1, fmaf(cw.z, v2, fmaf(cw.w, v3, acc[r]))));
        }
    }
    float* hsb = &ks2[0][0][0];              // reuse K-tile LDS as h[64][132]
    #pragma unroll
    for (int r = 0; r < 32; ++r) {
        const int row = g * 32 + r;
        hsb[row * 132 + c] = acc[r] * invr[row];
    }
    __syncthreads();

    // --- fused per-head LayerNorm + output (b,s,h,c) ---
    {
        float vals[32];
        float sum = 0.f, sq = 0.f;
        #pragma unroll
        for (int e = 0; e < 8; ++e) {
            const float4 x = *reinterpret_cast<const float4*>(&hsb[i * 132 + qq * 32 + e * 4]);
            vals[e*4+0] = x.x; vals[e*4+1] = x.y; vals[e*4+2] = x.z; vals[e*4+3] = x.w;
            sum += x.x + x.y + x.z + x.w;
            sq = fmaf(x.x, x.x, fmaf(x.y, x.y, fmaf(x.z, x.z, fmaf(x.w, x.w, sq))));
        }
        sum += __shfl_xor(sum, 1, 64); sum += __shfl_xor(sum, 2, 64);
        sq  += __shfl_xor(sq, 1, 64);  sq  += __shfl_xor(sq, 2, 64);
        const float mu = sum * (1.0f / 128.0f);
        const float var = sq * (1.0f / 128.0f) - mu * mu;
        const float rstd = rsqrtf(var + 1e-5f);
        float* op = out + ((b * SS + i) * NHH + h) * DHH + qq * 32;
        const float* wp = lnw + h * DHH + qq * 32;
        const float* bp = lnb + h * DHH + qq * 32;
        #pragma unroll
        for (int e = 0; e < 8; ++e) {
            float4 o;
            o.x = (vals[e*4+0] - mu) * rstd * (1.0f + wp[e*4+0]) + bp[e*4+0];
            o.y = (vals[e*4+1] - mu) * rstd * (1.0f + wp[e*4+1]) + bp[e*4+1];
            o.z = (vals[e*4+2] - mu) * rstd * (1.0f + wp[e*4+2]) + bp[e*4+2];
            o.w = (vals[e*4+3] - mu) * rstd * (1.0f + wp[e*4+3]) + bp[e*4+3];
            *reinterpret_cast<float4*>(op + e * 4) = o;
        }
    }
}

extern "C" void kernel_launch(void* const* d_in, const int* in_sizes, int n_in,
                              void* d_out, int out_size, void* d_ws, size_t ws_size,
                              hipStream_t stream) {
    const float* q   = (const float*)d_in[0];
    const float* k   = (const float*)d_in[1];
    const float* v   = (const float*)d_in[2];
    const float* igw = (const float*)d_in[3];
    const float* igb = (const float*)d_in[4];
    const float* fgw = (const float*)d_in[5];
    const float* fgb = (const float*)d_in[6];
    const float* rpe = (const float*)d_in[7];
    const float* lnw = (const float*)d_in[8];
    const float* lnb = (const float*)d_in[9];
    const int*  hops = (const int*)d_in[10];
    float* out = (float*)d_out;

    // workspace layout (floats): ig[256*8*64] | pmax[256*8*64] | csum[256*8*65] | khop[256*8*64*64]
    float* ig_ws   = (float*)d_ws;
    float* pmax_ws = ig_ws + 131072;
    float* csum_ws = pmax_ws + 131072;
    float* khop_ws = csum_ws + 133120;   // total ~34.3 MB

    hipLaunchKernelGGL(k_gates, dim3(BB), dim3(256), 0, stream,
                       q, k, v, igw, igb, fgw, fgb, ig_ws, csum_ws, pmax_ws);
    hipLaunchKernelGGL(k_khop, dim3(SS, NHH), dim3(256), 0, stream,
                       q, rpe, hops, khop_ws);
    hipLaunchKernelGGL(k_attn, dim3(BB * NHH), dim3(256), 0, stream,
                       q, k, v, lnw, lnb, ig_ws, csum_ws, pmax_ws, khop_ws, out);
}

// Round 2
// 414.752 us; speedup vs baseline: 1.3763x; 1.3763x over previous
//
#include <hip/hip_runtime.h>
#include <math.h>

#define BB 256
#define SS 64
#define DIMM 1024
#define NHH 8
#define DHH 128

__device__ __forceinline__ float logsigf(float x) {
    return fminf(x, 0.0f) - log1pf(__expf(-fabsf(x)));
}

// Kernel 1a: gate GEMM partials. 8192 waves: wave = (b, ksl), ksl in [0,32) owns a
// 96-float K-slice; lane = s. Weight addresses are wave-uniform (readfirstlane) ->
// scalar s_load_dwordx4; X loads are per-lane float4.
__global__ __launch_bounds__(256) void k_gates_partial(
    const float* __restrict__ q, const float* __restrict__ k, const float* __restrict__ v,
    const float* __restrict__ igw, const float* __restrict__ fgw,
    float* __restrict__ part)
{
    const int t = threadIdx.x;
    const int s = t & 63;
    const int gw = blockIdx.x * 4 + (t >> 6);
    const int b   = __builtin_amdgcn_readfirstlane(gw >> 5);
    const int ksl = __builtin_amdgcn_readfirstlane(gw & 31);
    const int rowbase = (b * SS + s) * DIMM;
    const int pbase = ksl * 96;

    float accI[8] = {0,0,0,0,0,0,0,0};
    float accF[8] = {0,0,0,0,0,0,0,0};
    #pragma unroll 4
    for (int it = 0; it < 24; ++it) {
        const int p = pbase + it * 4;
        const float* src;
        if (p < DIMM)        src = q + rowbase + p;
        else if (p < 2*DIMM) src = k + rowbase + (p - DIMM);
        else                 src = v + rowbase + (p - 2*DIMM);
        const float4 x = *reinterpret_cast<const float4*>(src);
        #pragma unroll
        for (int h = 0; h < 8; ++h) {
            const float* wi = igw + h * 3072 + p;
            const float* wf = fgw + h * 3072 + p;
            accI[h] = fmaf(x.x, wi[0], fmaf(x.y, wi[1], fmaf(x.z, wi[2], fmaf(x.w, wi[3], accI[h]))));
            accF[h] = fmaf(x.x, wf[0], fmaf(x.y, wf[1], fmaf(x.z, wf[2], fmaf(x.w, wf[3], accF[h]))));
        }
    }
    float* pb = part + ((size_t)(ksl * 256 + b) * 16) * 64 + s;
    #pragma unroll
    for (int h = 0; h < 8; ++h) {
        pb[h * 64]       = accI[h];
        pb[(8 + h) * 64] = accF[h];
    }
}

// Kernel 1b: reduce 32 K-slice partials, then log-sigmoid + cumsum + prefix-max scan.
__global__ __launch_bounds__(256) void k_gates_final(
    const float* __restrict__ part, const float* __restrict__ igb, const float* __restrict__ fgb,
    float* __restrict__ ig_ws, float* __restrict__ csum_ws, float* __restrict__ pmax_ws)
{
    const int b = blockIdx.x;
    const int t = threadIdx.x;
    __shared__ float red[16][66];
    #pragma unroll
    for (int u = 0; u < 4; ++u) {
        const int idx = u * 256 + t;
        const int out = idx >> 6, s = idx & 63;
        float sum = 0.0f;
        #pragma unroll 8
        for (int ksl = 0; ksl < 32; ++ksl)
            sum += part[((size_t)(ksl * 256 + b) * 16 + out) * 64 + s];
        red[out][s] = sum;
    }
    __syncthreads();
    if (t < 64) {
        const int s = t;
        #pragma unroll
        for (int h = 0; h < 8; ++h) {
            float ig = red[h][s]     + igb[h];
            float fg = red[8 + h][s] + fgb[h];
            float lf = logsigf(fg);
            float cs = lf;
            #pragma unroll
            for (int d = 1; d < 64; d <<= 1) {
                float o = __shfl_up(cs, (unsigned)d, 64);
                if (s >= d) cs += o;
            }
            float pm = ig - cs;
            #pragma unroll
            for (int d = 1; d < 64; d <<= 1) {
                float o = __shfl_up(pm, (unsigned)d, 64);
                if (s >= d) pm = fmaxf(pm, o);
            }
            const int base = b * NHH + h;
            ig_ws[base * SS + s] = ig;
            csum_ws[base * 65 + s + 1] = cs;
            if (s == 0) csum_ws[base * 65] = 0.0f;
            pmax_ws[base * SS + s] = pm;
        }
    }
}

// Kernel 2: khop[b][h][v][m] = dot(q[b,v,h*DH:], rpe[hops[v,m], h*DH:]) for m <= v.
// Block (v,h), 512 threads: thread = (mq = t>>7 owning m4 in {mq, mq+4, mq+8, mq+12},
// bb = t&127 owning batches bb and bb+128). PE row-major in LDS, broadcast reads.
__global__ __launch_bounds__(512) void k_khop(
    const float* __restrict__ q, const float* __restrict__ rpe, const int* __restrict__ hops,
    float* __restrict__ khop_ws)
{
    const int v = blockIdx.x;
    const int h = blockIdx.y;
    const int t = threadIdx.x;
    __shared__ float pe[SS][132];
    const int nelem = (v + 1) * DHH;
    for (int idx = t; idx < nelem; idx += 512) {
        const int m = idx >> 7, c = idx & 127;
        pe[m][c] = rpe[hops[v * SS + m] * DIMM + h * DHH + c];
    }
    __syncthreads();

    const int bb = t & 127;
    const int mq = t >> 7;   // wave-uniform (waves 0-1 -> 0, ... 6-7 -> 3)
    float a0[16], a1[16];
    #pragma unroll
    for (int e = 0; e < 16; ++e) { a0[e] = 0.0f; a1[e] = 0.0f; }
    const float* q0 = q + ((size_t)(bb)       * SS + v) * DIMM + h * DHH;
    const float* q1 = q + ((size_t)(bb + 128) * SS + v) * DIMM + h * DHH;

    #pragma unroll
    for (int c0 = 0; c0 < 4; ++c0) {
        float4 qa[8], qb[8];
        #pragma unroll
        for (int e = 0; e < 8; ++e) {
            qa[e] = *reinterpret_cast<const float4*>(q0 + c0 * 32 + e * 4);
            qb[e] = *reinterpret_cast<const float4*>(q1 + c0 * 32 + e * 4);
        }
        #pragma unroll
        for (int g = 0; g < 4; ++g) {
            const int m0 = (mq + g * 4) * 4;
            if (m0 > v) continue;            // wave-uniform branch
            #pragma unroll
            for (int mm = 0; mm < 4; ++mm) {
                float s0 = 0.0f, s1 = 0.0f;
                #pragma unroll
                for (int e = 0; e < 8; ++e) {
                    const float4 p4 = *reinterpret_cast<const float4*>(&pe[m0 + mm][c0 * 32 + e * 4]);
                    s0 = fmaf(qa[e].x, p4.x, fmaf(qa[e].y, p4.y, fmaf(qa[e].z, p4.z, fmaf(qa[e].w, p4.w, s0))));
                    s1 = fmaf(qb[e].x, p4.x, fmaf(qb[e].y, p4.y, fmaf(qb[e].z, p4.z, fmaf(qb[e].w, p4.w, s1))));
                }
                a0[g * 4 + mm] += s0;
                a1[g * 4 + mm] += s1;
            }
        }
    }
    #pragma unroll
    for (int g = 0; g < 4; ++g) {
        const int m0 = (mq + g * 4) * 4;
        if (m0 > v) continue;
        float* op0 = khop_ws + (((size_t)bb         * NHH + h) * SS + v) * SS + m0;
        float* op1 = khop_ws + (((size_t)(bb + 128) * NHH + h) * SS + v) * SS + m0;
        if (m0 + 3 <= v) {
            *reinterpret_cast<float4*>(op0) = make_float4(a0[g*4+0], a0[g*4+1], a0[g*4+2], a0[g*4+3]);
            *reinterpret_cast<float4*>(op1) = make_float4(a1[g*4+0], a1[g*4+1], a1[g*4+2], a1[g*4+3]);
        } else {
            #pragma unroll
            for (int mm = 0; mm < 4; ++mm) {
                if (m0 + mm <= v) { op0[mm] = a0[g*4+mm]; op1[mm] = a1[g*4+mm]; }
            }
        }
    }
}

// Kernel 3: per (b,h): C = (QK^T + khop) * D, normalize, PV, fused per-head LayerNorm.
__global__ __launch_bounds__(256) void k_attn(
    const float* __restrict__ q, const float* __restrict__ k, const float* __restrict__ v,
    const float* __restrict__ lnw, const float* __restrict__ lnb,
    const float* __restrict__ ig_ws, const float* __restrict__ csum_ws,
    const float* __restrict__ pmax_ws, const float* __restrict__ khop_ws,
    float* __restrict__ out)
{
    const int bid = blockIdx.x;
    const int b = bid >> 3, h = bid & 7;
    const int t = threadIdx.x;
    __shared__ float ks2[SS][4][36];    // K tile in 32-wide column slices (conflict-free b128)
    __shared__ float cs[SS][68];        // khop preload, overwritten in place by C
    __shared__ float csum_s[65];
    __shared__ float ig_s[64];
    __shared__ float pmax_s[64];
    __shared__ float invr[64];
    const float rs_dh = 0.08838834764831845f;  // 1/sqrt(128)

    // --- stage K (scaled), khop, gate vectors ---
    for (int idx = t; idx < SS * 32; idx += 256) {
        const int row = idx >> 5, c4 = idx & 31;
        float4 kv = *reinterpret_cast<const float4*>(k + ((b * SS + row) * DIMM + h * DHH + c4 * 4));
        kv.x *= rs_dh; kv.y *= rs_dh; kv.z *= rs_dh; kv.w *= rs_dh;
        *reinterpret_cast<float4*>(&ks2[row][c4 >> 3][(c4 & 7) * 4]) = kv;
    }
    const float* khb = khop_ws + (b * NHH + h) * SS * SS;
    for (int idx = t; idx < SS * 16; idx += 256) {
        const int row = idx >> 4, j4 = idx & 15;
        *reinterpret_cast<float4*>(&cs[row][j4 * 4]) =
            *reinterpret_cast<const float4*>(khb + row * SS + j4 * 4);
    }
    const int cb = b * NHH + h;
    if (t < 65) csum_s[t] = csum_ws[cb * 65 + t];
    if (t >= 128 && t < 192) ig_s[t - 128] = ig_ws[cb * SS + (t - 128)];
    if (t >= 192) pmax_s[t - 192] = pmax_ws[cb * SS + (t - 192)];

    const int i = t >> 2, qq = t & 3;   // quad-per-row; qq owns a 32-wide c-slice
    float4 qr[8];
    {
        const float4* qp = reinterpret_cast<const float4*>(q + ((b * SS + i) * DIMM + h * DHH + qq * 32));
        #pragma unroll
        for (int e = 0; e < 8; ++e) qr[e] = qp[e];
    }
    __syncthreads();

    // --- C phase: lower-triangular (qk + khop) * exp(logD - m_i) ---
    const float m_i = csum_s[i + 1] + pmax_s[i];
    float rs = 0.0f;
    for (int j = 0; j <= i; ++j) {
        float part = 0.0f;
        #pragma unroll
        for (int e = 0; e < 8; ++e) {
            const float4 kk = *reinterpret_cast<const float4*>(&ks2[j][qq][e * 4]);
            part = fmaf(qr[e].x, kk.x, part); part = fmaf(qr[e].y, kk.y, part);
            part = fmaf(qr[e].z, kk.z, part); part = fmaf(qr[e].w, kk.w, part);
        }
        part += __shfl_xor(part, 1, 64);
        part += __shfl_xor(part, 2, 64);
        if ((j & 3) == qq) {                 // finalize lane for this j
            const float sc = part + cs[i][j];
            const float logD = csum_s[i + 1] - csum_s[j + 1] + ig_s[j];
            const float C = sc * __expf(logD - m_i);
            rs += C;
            cs[i][j] = C;
        }
    }
    // zero the upper triangle of this row (my residue class)
    for (int j = i + 1 + ((qq - (i + 1)) & 3); j < SS; j += 4) cs[i][j] = 0.0f;
    rs += __shfl_xor(rs, 1, 64);
    rs += __shfl_xor(rs, 2, 64);
    const float nrm = fmaxf(fabsf(rs), __expf(-m_i));
    if (qq == 0) invr[i] = 1.0f / (nrm + 1e-6f);
    __syncthreads();

    // --- PV: h[i][c] = sum_j C[i][j] * v[j][c]; thread = (row-group g, column c) ---
    const int g = t >> 7, c = t & 127;
    float acc[32];
    #pragma unroll
    for (int r = 0; r < 32; ++r) acc[r] = 0.0f;
    const int j4max = (g == 0) ? 8 : 16;     // rows 0..31 only need j<32
    const float* vb = v + (b * SS) * DIMM + h * DHH + c;
    for (int j4 = 0; j4 < j4max; ++j4) {
        const float v0 = vb[(j4 * 4 + 0) * DIMM];
        const float v1 = vb[(j4 * 4 + 1) * DIMM];
        const float v2 = vb[(j4 * 4 + 2) * DIMM];
        const float v3 = vb[(j4 * 4 + 3) * DIMM];
        #pragma unroll
        for (int r = 0; r < 32; ++r) {
            const float4 cw = *reinterpret_cast<const float4*>(&cs[g * 32 + r][j4 * 4]);
            acc[r] = fmaf(cw.x, v0, fmaf(cw.y, v1, fmaf(cw.z, v2, fmaf(cw.w, v3, acc[r]))));
        }
    }
    float* hsb = &ks2[0][0][0];              // reuse K-tile LDS as h[64][132]
    #pragma unroll
    for (int r = 0; r < 32; ++r) {
        const int row = g * 32 + r;
        hsb[row * 132 + c] = acc[r] * invr[row];
    }
    __syncthreads();

    // --- fused per-head LayerNorm + output (b,s,h,c) ---
    {
        float vals[32];
        float sum = 0.f, sq = 0.f;
        #pragma unroll
        for (int e = 0; e < 8; ++e) {
            const float4 x = *reinterpret_cast<const float4*>(&hsb[i * 132 + qq * 32 + e * 4]);
            vals[e*4+0] = x.x; vals[e*4+1] = x.y; vals[e*4+2] = x.z; vals[e*4+3] = x.w;
            sum += x.x + x.y + x.z + x.w;
            sq = fmaf(x.x, x.x, fmaf(x.y, x.y, fmaf(x.z, x.z, fmaf(x.w, x.w, sq))));
        }
        sum += __shfl_xor(sum, 1, 64); sum += __shfl_xor(sum, 2, 64);
        sq  += __shfl_xor(sq, 1, 64);  sq  += __shfl_xor(sq, 2, 64);
        const float mu = sum * (1.0f / 128.0f);
        const float var = sq * (1.0f / 128.0f) - mu * mu;
        const float rstd = rsqrtf(var + 1e-5f);
        float* op = out + ((b * SS + i) * NHH + h) * DHH + qq * 32;
        const float* wp = lnw + h * DHH + qq * 32;
        const float* bp = lnb + h * DHH + qq * 32;
        #pragma unroll
        for (int e = 0; e < 8; ++e) {
            float4 o;
            o.x = (vals[e*4+0] - mu) * rstd * (1.0f + wp[e*4+0]) + bp[e*4+0];
            o.y = (vals[e*4+1] - mu) * rstd * (1.0f + wp[e*4+1]) + bp[e*4+1];
            o.z = (vals[e*4+2] - mu) * rstd * (1.0f + wp[e*4+2]) + bp[e*4+2];
            o.w = (vals[e*4+3] - mu) * rstd * (1.0f + wp[e*4+3]) + bp[e*4+3];
            *reinterpret_cast<float4*>(op + e * 4) = o;
        }
    }
}

extern "C" void kernel_launch(void* const* d_in, const int* in_sizes, int n_in,
                              void* d_out, int out_size, void* d_ws, size_t ws_size,
                              hipStream_t stream) {
    const float* q   = (const float*)d_in[0];
    const float* k   = (const float*)d_in[1];
    const float* v   = (const float*)d_in[2];
    const float* igw = (const float*)d_in[3];
    const float* igb = (const float*)d_in[4];
    const float* fgw = (const float*)d_in[5];
    const float* fgb = (const float*)d_in[6];
    const float* rpe = (const float*)d_in[7];
    const float* lnw = (const float*)d_in[8];
    const float* lnb = (const float*)d_in[9];
    const int*  hops = (const int*)d_in[10];
    float* out = (float*)d_out;

    // workspace layout (floats):
    //   ig[256*8*64] | pmax[256*8*64] | csum[256*8*65] | khop/partial[8.4M] (aliased:
    //   gate partials are consumed by k_gates_final BEFORE k_khop overwrites the region;
    //   same-stream ordering guarantees this)
    float* ig_ws   = (float*)d_ws;
    float* pmax_ws = ig_ws + 131072;
    float* csum_ws = pmax_ws + 131072;
    float* khop_ws = csum_ws + 133120;   // also the gate-partial buffer

    hipLaunchKernelGGL(k_gates_partial, dim3(2048), dim3(256), 0, stream,
                       q, k, v, igw, fgw, khop_ws);
    hipLaunchKernelGGL(k_gates_final, dim3(BB), dim3(256), 0, stream,
                       khop_ws, igb, fgb, ig_ws, csum_ws, pmax_ws);
    hipLaunchKernelGGL(k_khop, dim3(SS, NHH), dim3(512), 0, stream,
                       q, rpe, hops, khop_ws);
    hipLaunchKernelGGL(k_attn, dim3(BB * NHH), dim3(256), 0, stream,
                       q, k, v, lnw, lnb, ig_ws, csum_ws, pmax_ws, khop_ws, out);
}

// Round 6
// 339.046 us; speedup vs baseline: 1.6836x; 1.2233x over previous
//
#include <hip/hip_runtime.h>
#include <math.h>

#define BB 256
#define SS 64
#define DIMM 1024
#define NHH 8
#define DHH 128

typedef short bf16x8 __attribute__((ext_vector_type(8)));
typedef float f32x4 __attribute__((ext_vector_type(4)));

__device__ __forceinline__ unsigned f2bf(float f) {   // bf16 bits (RNE) in low 16
    union { float f; unsigned u; } x{f};
    return (x.u + 0x7FFFu + ((x.u >> 16) & 1u)) >> 16;
}
__device__ __forceinline__ unsigned pk2(float lo, float hi) {
    return f2bf(lo) | (f2bf(hi) << 16);
}
__device__ __forceinline__ float logsigf(float x) {
    return fminf(x, 0.0f) - log1pf(__expf(-fabsf(x)));
}

// ---------------------------------------------------------------------------
// Kernel 1a: gate GEMM partials via MFMA (validated by r4==r5 absmax identity).
// grid = 1024 (b=bid&255, ksl=bid>>8). M=64, N=16 (8 ig + 8 fg), K=768 slice.
// partials layout: [ksl][b][s][16]
// ---------------------------------------------------------------------------
__global__ __launch_bounds__(256) void k_gate_mfma(
    const float* __restrict__ q, const float* __restrict__ k, const float* __restrict__ v,
    const float* __restrict__ igw, const float* __restrict__ fgw,
    float* __restrict__ part)
{
    __shared__ unsigned short Xs[64 * 264];   // [64][256+8] bf16
    __shared__ unsigned short Ws[16 * 264];
    const int b = blockIdx.x & 255;
    const int ksl = blockIdx.x >> 8;
    const int t = threadIdx.x;
    const int w = t >> 6, l = t & 63, c = l & 15, g = l >> 4;

    f32x4 acc;
    acc[0] = 0.f; acc[1] = 0.f; acc[2] = 0.f; acc[3] = 0.f;

    for (int step = 0; step < 3; ++step) {
        const int kc = ksl * 3 + step;            // global 256-col chunk 0..11
        const int tensor = kc >> 2;
        const float* src = (tensor == 0) ? q : (tensor == 1) ? k : v;
        src += ((size_t)b * 64) * 1024 + (kc & 3) * 256;
        {   // stage X[64][256]
            const int row = t >> 2, seg = t & 3;
            const float* rp = src + row * 1024;
            #pragma unroll
            for (int e = 0; e < 16; ++e) {
                const int col = e * 16 + seg * 4;
                const float4 x = *reinterpret_cast<const float4*>(rp + col);
                unsigned* dp = reinterpret_cast<unsigned*>(&Xs[row * 264 + col]);
                dp[0] = pk2(x.x, x.y); dp[1] = pk2(x.z, x.w);
            }
        }
        {   // stage W[16][256]
            const int o = t >> 4, wseg = t & 15;
            const int p0 = ksl * 768 + step * 256;
            const float* wp = (o < 8 ? igw + o * 3072 : fgw + (o - 8) * 3072) + p0;
            #pragma unroll
            for (int e = 0; e < 4; ++e) {
                const int col = e * 64 + wseg * 4;
                const float4 x = *reinterpret_cast<const float4*>(wp + col);
                unsigned* dp = reinterpret_cast<unsigned*>(&Ws[o * 264 + col]);
                dp[0] = pk2(x.x, x.y); dp[1] = pk2(x.z, x.w);
            }
        }
        __syncthreads();
        #pragma unroll
        for (int kk = 0; kk < 8; ++kk) {
            bf16x8 a  = *reinterpret_cast<const bf16x8*>(&Xs[(16 * w + c) * 264 + 32 * kk + 8 * g]);
            bf16x8 bw = *reinterpret_cast<const bf16x8*>(&Ws[c * 264 + 32 * kk + 8 * g]);
            acc = __builtin_amdgcn_mfma_f32_16x16x32_bf16(a, bw, acc, 0, 0, 0);
        }
        __syncthreads();
    }
    float* pb = part + (((size_t)ksl * 256 + b) * 64) * 16;
    #pragma unroll
    for (int reg = 0; reg < 4; ++reg) {
        const int s = 16 * w + 4 * g + reg;    // D: col=lane&15, row=4*(lane>>4)+reg
        pb[s * 16 + c] = acc[reg];
    }
}

// ---------------------------------------------------------------------------
// Kernel 1b: reduce 4 K-slice partials + bias, log-sigmoid, cumsum, prefix-max.
// ---------------------------------------------------------------------------
__global__ __launch_bounds__(256) void k_gates_final(
    const float* __restrict__ part, const float* __restrict__ igb, const float* __restrict__ fgb,
    float* __restrict__ ig_ws, float* __restrict__ csum_ws, float* __restrict__ pmax_ws)
{
    const int b = blockIdx.x;
    const int t = threadIdx.x;
    __shared__ float red[64][18];
    {
        const int s = t >> 2, oq = t & 3;
        float4 sum = make_float4(0.f, 0.f, 0.f, 0.f);
        #pragma unroll
        for (int ksl = 0; ksl < 4; ++ksl) {
            const float4 p = *reinterpret_cast<const float4*>(
                part + (((size_t)ksl * 256 + b) * 64 + s) * 16 + oq * 4);
            sum.x += p.x; sum.y += p.y; sum.z += p.z; sum.w += p.w;
        }
        red[s][oq * 4 + 0] = sum.x; red[s][oq * 4 + 1] = sum.y;
        red[s][oq * 4 + 2] = sum.z; red[s][oq * 4 + 3] = sum.w;
    }
    __syncthreads();
    if (t < 64) {
        const int s = t;
        #pragma unroll
        for (int h = 0; h < 8; ++h) {
            float ig = red[s][h]     + igb[h];
            float fg = red[s][8 + h] + fgb[h];
            float lf = logsigf(fg);
            float cs = lf;
            #pragma unroll
            for (int d = 1; d < 64; d <<= 1) {
                float o = __shfl_up(cs, (unsigned)d, 64);
                if (s >= d) cs += o;
            }
            float pm = ig - cs;
            #pragma unroll
            for (int d = 1; d < 64; d <<= 1) {
                float o = __shfl_up(pm, (unsigned)d, 64);
                if (s >= d) pm = fmaxf(pm, o);
            }
            const int base = b * NHH + h;
            ig_ws[base * SS + s] = ig;
            csum_ws[base * 65 + s + 1] = cs;
            if (s == 0) csum_ws[base * 65] = 0.0f;
            pmax_ws[base * SS + s] = pm;
        }
    }
}

// ---------------------------------------------------------------------------
// Kernel 2 (r2-PROVEN, exact): khop[b][h][v][m] f32.
// ---------------------------------------------------------------------------
__global__ __launch_bounds__(512) void k_khop(
    const float* __restrict__ q, const float* __restrict__ rpe, const int* __restrict__ hops,
    float* __restrict__ khop_ws)
{
    const int v = blockIdx.x;
    const int h = blockIdx.y;
    const int t = threadIdx.x;
    __shared__ float pe[SS][132];
    const int nelem = (v + 1) * DHH;
    for (int idx = t; idx < nelem; idx += 512) {
        const int m = idx >> 7, cc = idx & 127;
        pe[m][cc] = rpe[hops[v * SS + m] * DIMM + h * DHH + cc];
    }
    __syncthreads();

    const int bb = t & 127;
    const int mq = t >> 7;   // wave-uniform
    float a0[16], a1[16];
    #pragma unroll
    for (int e = 0; e < 16; ++e) { a0[e] = 0.0f; a1[e] = 0.0f; }
    const float* q0 = q + ((size_t)(bb)       * SS + v) * DIMM + h * DHH;
    const float* q1 = q + ((size_t)(bb + 128) * SS + v) * DIMM + h * DHH;

    #pragma unroll
    for (int c0 = 0; c0 < 4; ++c0) {
        float4 qa[8], qb[8];
        #pragma unroll
        for (int e = 0; e < 8; ++e) {
            qa[e] = *reinterpret_cast<const float4*>(q0 + c0 * 32 + e * 4);
            qb[e] = *reinterpret_cast<const float4*>(q1 + c0 * 32 + e * 4);
        }
        #pragma unroll
        for (int g = 0; g < 4; ++g) {
            const int m0 = (mq + g * 4) * 4;
            if (m0 > v) continue;
            #pragma unroll
            for (int mm = 0; mm < 4; ++mm) {
                float s0 = 0.0f, s1 = 0.0f;
                #pragma unroll
                for (int e = 0; e < 8; ++e) {
                    const float4 p4 = *reinterpret_cast<const float4*>(&pe[m0 + mm][c0 * 32 + e * 4]);
                    s0 = fmaf(qa[e].x, p4.x, fmaf(qa[e].y, p4.y, fmaf(qa[e].z, p4.z, fmaf(qa[e].w, p4.w, s0))));
                    s1 = fmaf(qb[e].x, p4.x, fmaf(qb[e].y, p4.y, fmaf(qb[e].z, p4.z, fmaf(qb[e].w, p4.w, s1))));
                }
                a0[g * 4 + mm] += s0;
                a1[g * 4 + mm] += s1;
            }
        }
    }
    #pragma unroll
    for (int g = 0; g < 4; ++g) {
        const int m0 = (mq + g * 4) * 4;
        if (m0 > v) continue;
        float* op0 = khop_ws + (((size_t)bb         * NHH + h) * SS + v) * SS + m0;
        float* op1 = khop_ws + (((size_t)(bb + 128) * NHH + h) * SS + v) * SS + m0;
        if (m0 + 3 <= v) {
            *reinterpret_cast<float4*>(op0) = make_float4(a0[g*4+0], a0[g*4+1], a0[g*4+2], a0[g*4+3]);
            *reinterpret_cast<float4*>(op1) = make_float4(a1[g*4+0], a1[g*4+1], a1[g*4+2], a1[g*4+3]);
        } else {
            #pragma unroll
            for (int mm = 0; mm < 4; ++mm) {
                if (m0 + mm <= v) { op0[mm] = a0[g*4+mm]; op1[mm] = a1[g*4+mm]; }
            }
        }
    }
}

// ---------------------------------------------------------------------------
// Kernel 3 (r2-PROVEN, exact): VALU attention, f32 khop staging.
// ---------------------------------------------------------------------------
__global__ __launch_bounds__(256) void k_attn(
    const float* __restrict__ q, const float* __restrict__ k, const float* __restrict__ v,
    const float* __restrict__ lnw, const float* __restrict__ lnb,
    const float* __restrict__ ig_ws, const float* __restrict__ csum_ws,
    const float* __restrict__ pmax_ws, const float* __restrict__ khop_ws,
    float* __restrict__ out)
{
    const int bid = blockIdx.x;
    const int b = bid >> 3, h = bid & 7;
    const int t = threadIdx.x;
    __shared__ float ks2[SS][4][36];    // K tile in 32-wide column slices
    __shared__ float cs[SS][68];        // khop preload, overwritten in place by C
    __shared__ float csum_s[65];
    __shared__ float ig_s[64];
    __shared__ float pmax_s[64];
    __shared__ float invr[64];
    const float rs_dh = 0.08838834764831845f;  // 1/sqrt(128)

    // --- stage K (scaled) ---
    for (int idx = t; idx < SS * 32; idx += 256) {
        const int row = idx >> 5, c4 = idx & 31;
        float4 kv = *reinterpret_cast<const float4*>(k + ((b * SS + row) * DIMM + h * DHH + c4 * 4));
        kv.x *= rs_dh; kv.y *= rs_dh; kv.z *= rs_dh; kv.w *= rs_dh;
        *reinterpret_cast<float4*>(&ks2[row][c4 >> 3][(c4 & 7) * 4]) = kv;
    }
    // --- stage khop (f32, r2 layout [b][h][v][m]) ---
    const float* khb = khop_ws + (b * NHH + h) * SS * SS;
    for (int idx = t; idx < SS * 16; idx += 256) {
        const int row = idx >> 4, j4 = idx & 15;
        *reinterpret_cast<float4*>(&cs[row][j4 * 4]) =
            *reinterpret_cast<const float4*>(khb + row * SS + j4 * 4);
    }
    const int cb = b * NHH + h;
    if (t < 65) csum_s[t] = csum_ws[cb * 65 + t];
    if (t >= 128 && t < 192) ig_s[t - 128] = ig_ws[cb * SS + (t - 128)];
    if (t >= 192) pmax_s[t - 192] = pmax_ws[cb * SS + (t - 192)];

    const int i = t >> 2, qq = t & 3;   // quad-per-row; qq owns a 32-wide c-slice
    float4 qr[8];
    {
        const float4* qp = reinterpret_cast<const float4*>(q + ((b * SS + i) * DIMM + h * DHH + qq * 32));
        #pragma unroll
        for (int e = 0; e < 8; ++e) qr[e] = qp[e];
    }
    __syncthreads();

    // --- C phase: lower-triangular (qk + khop) * exp(logD - m_i) ---
    const float m_i = csum_s[i + 1] + pmax_s[i];
    float rs = 0.0f;
    for (int j = 0; j <= i; ++j) {
        float part = 0.0f;
        #pragma unroll
        for (int e = 0; e < 8; ++e) {
            const float4 kk = *reinterpret_cast<const float4*>(&ks2[j][qq][e * 4]);
            part = fmaf(qr[e].x, kk.x, part); part = fmaf(qr[e].y, kk.y, part);
            part = fmaf(qr[e].z, kk.z, part); part = fmaf(qr[e].w, kk.w, part);
        }
        part += __shfl_xor(part, 1, 64);
        part += __shfl_xor(part, 2, 64);
        if ((j & 3) == qq) {                 // finalize lane for this j
            const float sc = part + cs[i][j];
            const float logD = csum_s[i + 1] - csum_s[j + 1] + ig_s[j];
            const float C = sc * __expf(logD - m_i);
            rs += C;
            cs[i][j] = C;
        }
    }
    // zero the upper triangle of this row (my residue class)
    for (int j = i + 1 + ((qq - (i + 1)) & 3); j < SS; j += 4) cs[i][j] = 0.0f;
    rs += __shfl_xor(rs, 1, 64);
    rs += __shfl_xor(rs, 2, 64);
    const float nrm = fmaxf(fabsf(rs), __expf(-m_i));
    if (qq == 0) invr[i] = 1.0f / (nrm + 1e-6f);
    __syncthreads();

    // --- PV: h[i][c] = sum_j C[i][j] * v[j][c] ---
    const int g = t >> 7, c = t & 127;
    float acc[32];
    #pragma unroll
    for (int r = 0; r < 32; ++r) acc[r] = 0.0f;
    const int j4max = (g == 0) ? 8 : 16;     // rows 0..31 only need j<32
    const float* vb = v + (b * SS) * DIMM + h * DHH + c;
    for (int j4 = 0; j4 < j4max; ++j4) {
        const float v0 = vb[(j4 * 4 + 0) * DIMM];
        const float v1 = vb[(j4 * 4 + 1) * DIMM];
        const float v2 = vb[(j4 * 4 + 2) * DIMM];
        const float v3 = vb[(j4 * 4 + 3) * DIMM];
        #pragma unroll
        for (int r = 0; r < 32; ++r) {
            const float4 cw = *reinterpret_cast<const float4*>(&cs[g * 32 + r][j4 * 4]);
            acc[r] = fmaf(cw.x, v0, fmaf(cw.y, v1, fmaf(cw.z, v2, fmaf(cw.w, v3, acc[r]))));
        }
    }
    float* hsb = &ks2[0][0][0];              // reuse K-tile LDS as h[64][132]
    #pragma unroll
    for (int r = 0; r < 32; ++r) {
        const int row = g * 32 + r;
        hsb[row * 132 + c] = acc[r] * invr[row];
    }
    __syncthreads();

    // --- fused per-head LayerNorm + output (b,s,h,c) ---
    {
        float vals[32];
        float sum = 0.f, sq = 0.f;
        #pragma unroll
        for (int e = 0; e < 8; ++e) {
            const float4 x = *reinterpret_cast<const float4*>(&hsb[i * 132 + qq * 32 + e * 4]);
            vals[e*4+0] = x.x; vals[e*4+1] = x.y; vals[e*4+2] = x.z; vals[e*4+3] = x.w;
            sum += x.x + x.y + x.z + x.w;
            sq = fmaf(x.x, x.x, fmaf(x.y, x.y, fmaf(x.z, x.z, fmaf(x.w, x.w, sq))));
        }
        sum += __shfl_xor(sum, 1, 64); sum += __shfl_xor(sum, 2, 64);
        sq  += __shfl_xor(sq, 1, 64);  sq  += __shfl_xor(sq, 2, 64);
        const float mu = sum * (1.0f / 128.0f);
        const float var = sq * (1.0f / 128.0f) - mu * mu;
        const float rstd = rsqrtf(var + 1e-5f);
        float* op = out + ((b * SS + i) * NHH + h) * DHH + qq * 32;
        const float* wp = lnw + h * DHH + qq * 32;
        const float* bp = lnb + h * DHH + qq * 32;
        #pragma unroll
        for (int e = 0; e < 8; ++e) {
            float4 o;
            o.x = (vals[e*4+0] - mu) * rstd * (1.0f + wp[e*4+0]) + bp[e*4+0];
            o.y = (vals[e*4+1] - mu) * rstd * (1.0f + wp[e*4+1]) + bp[e*4+1];
            o.z = (vals[e*4+2] - mu) * rstd * (1.0f + wp[e*4+2]) + bp[e*4+2];
            o.w = (vals[e*4+3] - mu) * rstd * (1.0f + wp[e*4+3]) + bp[e*4+3];
            *reinterpret_cast<float4*>(op + e * 4) = o;
        }
    }
}

extern "C" void kernel_launch(void* const* d_in, const int* in_sizes, int n_in,
                              void* d_out, int out_size, void* d_ws, size_t ws_size,
                              hipStream_t stream) {
    const float* q   = (const float*)d_in[0];
    const float* k   = (const float*)d_in[1];
    const float* v   = (const float*)d_in[2];
    const float* igw = (const float*)d_in[3];
    const float* igb = (const float*)d_in[4];
    const float* fgw = (const float*)d_in[5];
    const float* fgb = (const float*)d_in[6];
    const float* rpe = (const float*)d_in[7];
    const float* lnw = (const float*)d_in[8];
    const float* lnb = (const float*)d_in[9];
    const int*  hops = (const int*)d_in[10];
    float* out = (float*)d_out;

    // ws (floats): ig[131072] | pmax[131072] | csum[133120] | REGION (aliased):
    //   gate-MFMA partials ([4][256][64][16] = 1.05M f32) consumed by
    //   k_gates_final BEFORE k_khop overwrites the region as khop_ws
    //   ([256][8][64][64] = 8.39M f32). Same-stream ordering guarantees this.
    float* ig_ws   = (float*)d_ws;
    float* pmax_ws = ig_ws + 131072;
    float* csum_ws = pmax_ws + 131072;
    float* part    = csum_ws + 133120;
    float* khop_ws = part;

    hipLaunchKernelGGL(k_gate_mfma, dim3(1024), dim3(256), 0, stream,
                       q, k, v, igw, fgw, part);
    hipLaunchKernelGGL(k_gates_final, dim3(BB), dim3(256), 0, stream,
                       part, igb, fgb, ig_ws, csum_ws, pmax_ws);
    hipLaunchKernelGGL(k_khop, dim3(SS, NHH), dim3(512), 0, stream,
                       q, rpe, hops, khop_ws);
    hipLaunchKernelGGL(k_attn, dim3(BB * NHH), dim3(256), 0, stream,
                       q, k, v, lnw, lnb, ig_ws, csum_ws, pmax_ws, khop_ws, out);
}

// Round 9
// 279.498 us; speedup vs baseline: 2.0423x; 1.2131x over previous
//
#include <hip/hip_runtime.h>
#include <math.h>

#define BB 256
#define SS 64
#define DIMM 1024
#define NHH 8
#define DHH 128

typedef short bf16x8 __attribute__((ext_vector_type(8)));
typedef float f32x4 __attribute__((ext_vector_type(4)));

__device__ __forceinline__ unsigned f2bf(float f) {   // bf16 bits (RNE) in low 16
    union { float f; unsigned u; } x{f};
    return (x.u + 0x7FFFu + ((x.u >> 16) & 1u)) >> 16;
}
__device__ __forceinline__ unsigned pk2(float lo, float hi) {
    return f2bf(lo) | (f2bf(hi) << 16);
}
__device__ __forceinline__ float bf2f(unsigned short b) {
    union { unsigned u; float f; } x{((unsigned)b) << 16};
    return x.f;
}
// split a,b into hi-bf16 pair and residual-lo-bf16 pair (packed words)
__device__ __forceinline__ void split2(float a, float b, unsigned& hi, unsigned& lo) {
    const unsigned ha = f2bf(a), hb = f2bf(b);
    hi = ha | (hb << 16);
    lo = pk2(a - bf2f((unsigned short)ha), b - bf2f((unsigned short)hb));
}
__device__ __forceinline__ float logsigf(float x) {
    return fminf(x, 0.0f) - log1pf(__expf(-fabsf(x)));
}

// ---------------------------------------------------------------------------
// Kernel 1a (r6-PROVEN): gate GEMM partials via MFMA.
// ---------------------------------------------------------------------------
__global__ __launch_bounds__(256) void k_gate_mfma(
    const float* __restrict__ q, const float* __restrict__ k, const float* __restrict__ v,
    const float* __restrict__ igw, const float* __restrict__ fgw,
    float* __restrict__ part)
{
    __shared__ unsigned short Xs[64 * 264];   // [64][256+8] bf16
    __shared__ unsigned short Ws[16 * 264];
    const int b = blockIdx.x & 255;
    const int ksl = blockIdx.x >> 8;
    const int t = threadIdx.x;
    const int w = t >> 6, l = t & 63, c = l & 15, g = l >> 4;

    f32x4 acc;
    acc[0] = 0.f; acc[1] = 0.f; acc[2] = 0.f; acc[3] = 0.f;

    for (int step = 0; step < 3; ++step) {
        const int kc = ksl * 3 + step;
        const int tensor = kc >> 2;
        const float* src = (tensor == 0) ? q : (tensor == 1) ? k : v;
        src += ((size_t)b * 64) * 1024 + (kc & 3) * 256;
        {
            const int row = t >> 2, seg = t & 3;
            const float* rp = src + row * 1024;
            #pragma unroll
            for (int e = 0; e < 16; ++e) {
                const int col = e * 16 + seg * 4;
                const float4 x = *reinterpret_cast<const float4*>(rp + col);
                unsigned* dp = reinterpret_cast<unsigned*>(&Xs[row * 264 + col]);
                dp[0] = pk2(x.x, x.y); dp[1] = pk2(x.z, x.w);
            }
        }
        {
            const int o = t >> 4, wseg = t & 15;
            const int p0 = ksl * 768 + step * 256;
            const float* wp = (o < 8 ? igw + o * 3072 : fgw + (o - 8) * 3072) + p0;
            #pragma unroll
            for (int e = 0; e < 4; ++e) {
                const int col = e * 64 + wseg * 4;
                const float4 x = *reinterpret_cast<const float4*>(wp + col);
                unsigned* dp = reinterpret_cast<unsigned*>(&Ws[o * 264 + col]);
                dp[0] = pk2(x.x, x.y); dp[1] = pk2(x.z, x.w);
            }
        }
        __syncthreads();
        #pragma unroll
        for (int kk = 0; kk < 8; ++kk) {
            bf16x8 a  = *reinterpret_cast<const bf16x8*>(&Xs[(16 * w + c) * 264 + 32 * kk + 8 * g]);
            bf16x8 bw = *reinterpret_cast<const bf16x8*>(&Ws[c * 264 + 32 * kk + 8 * g]);
            acc = __builtin_amdgcn_mfma_f32_16x16x32_bf16(a, bw, acc, 0, 0, 0);
        }
        __syncthreads();
    }
    float* pb = part + (((size_t)ksl * 256 + b) * 64) * 16;
    #pragma unroll
    for (int reg = 0; reg < 4; ++reg) {
        const int s = 16 * w + 4 * g + reg;
        pb[s * 16 + c] = acc[reg];
    }
}

// ---------------------------------------------------------------------------
// Kernel 1b (r6-PROVEN): reduce partials + bias, log-sigmoid, cumsum, pmax.
// ---------------------------------------------------------------------------
__global__ __launch_bounds__(256) void k_gates_final(
    const float* __restrict__ part, const float* __restrict__ igb, const float* __restrict__ fgb,
    float* __restrict__ ig_ws, float* __restrict__ csum_ws, float* __restrict__ pmax_ws)
{
    const int b = blockIdx.x;
    const int t = threadIdx.x;
    __shared__ float red[64][18];
    {
        const int s = t >> 2, oq = t & 3;
        float4 sum = make_float4(0.f, 0.f, 0.f, 0.f);
        #pragma unroll
        for (int ksl = 0; ksl < 4; ++ksl) {
            const float4 p = *reinterpret_cast<const float4*>(
                part + (((size_t)ksl * 256 + b) * 64 + s) * 16 + oq * 4);
            sum.x += p.x; sum.y += p.y; sum.z += p.z; sum.w += p.w;
        }
        red[s][oq * 4 + 0] = sum.x; red[s][oq * 4 + 1] = sum.y;
        red[s][oq * 4 + 2] = sum.z; red[s][oq * 4 + 3] = sum.w;
    }
    __syncthreads();
    if (t < 64) {
        const int s = t;
        #pragma unroll
        for (int h = 0; h < 8; ++h) {
            float ig = red[s][h]     + igb[h];
            float fg = red[s][8 + h] + fgb[h];
            float lf = logsigf(fg);
            float cs = lf;
            #pragma unroll
            for (int d = 1; d < 64; d <<= 1) {
                float o = __shfl_up(cs, (unsigned)d, 64);
                if (s >= d) cs += o;
            }
            float pm = ig - cs;
            #pragma unroll
            for (int d = 1; d < 64; d <<= 1) {
                float o = __shfl_up(pm, (unsigned)d, 64);
                if (s >= d) pm = fmaxf(pm, o);
            }
            const int base = b * NHH + h;
            ig_ws[base * SS + s] = ig;
            csum_ws[base * 65 + s + 1] = cs;
            if (s == 0) csum_ws[base * 65] = 0.0f;
            pmax_ws[base * SS + s] = pm;
        }
    }
}

// ---------------------------------------------------------------------------
// Kernel 2 (r6-PROVEN): khop[b][h][v][m] f32.
// ---------------------------------------------------------------------------
__global__ __launch_bounds__(512) void k_khop(
    const float* __restrict__ q, const float* __restrict__ rpe, const int* __restrict__ hops,
    float* __restrict__ khop_ws)
{
    const int v = blockIdx.x;
    const int h = blockIdx.y;
    const int t = threadIdx.x;
    __shared__ float pe[SS][132];
    const int nelem = (v + 1) * DHH;
    for (int idx = t; idx < nelem; idx += 512) {
        const int m = idx >> 7, cc = idx & 127;
        pe[m][cc] = rpe[hops[v * SS + m] * DIMM + h * DHH + cc];
    }
    __syncthreads();

    const int bb = t & 127;
    const int mq = t >> 7;
    float a0[16], a1[16];
    #pragma unroll
    for (int e = 0; e < 16; ++e) { a0[e] = 0.0f; a1[e] = 0.0f; }
    const float* q0 = q + ((size_t)(bb)       * SS + v) * DIMM + h * DHH;
    const float* q1 = q + ((size_t)(bb + 128) * SS + v) * DIMM + h * DHH;

    #pragma unroll
    for (int c0 = 0; c0 < 4; ++c0) {
        float4 qa[8], qb[8];
        #pragma unroll
        for (int e = 0; e < 8; ++e) {
            qa[e] = *reinterpret_cast<const float4*>(q0 + c0 * 32 + e * 4);
            qb[e] = *reinterpret_cast<const float4*>(q1 + c0 * 32 + e * 4);
        }
        #pragma unroll
        for (int g = 0; g < 4; ++g) {
            const int m0 = (mq + g * 4) * 4;
            if (m0 > v) continue;
            #pragma unroll
            for (int mm = 0; mm < 4; ++mm) {
                float s0 = 0.0f, s1 = 0.0f;
                #pragma unroll
                for (int e = 0; e < 8; ++e) {
                    const float4 p4 = *reinterpret_cast<const float4*>(&pe[m0 + mm][c0 * 32 + e * 4]);
                    s0 = fmaf(qa[e].x, p4.x, fmaf(qa[e].y, p4.y, fmaf(qa[e].z, p4.z, fmaf(qa[e].w, p4.w, s0))));
                    s1 = fmaf(qb[e].x, p4.x, fmaf(qb[e].y, p4.y, fmaf(qb[e].z, p4.z, fmaf(qb[e].w, p4.w, s1))));
                }
                a0[g * 4 + mm] += s0;
                a1[g * 4 + mm] += s1;
            }
        }
    }
    #pragma unroll
    for (int g = 0; g < 4; ++g) {
        const int m0 = (mq + g * 4) * 4;
        if (m0 > v) continue;
        float* op0 = khop_ws + (((size_t)bb         * NHH + h) * SS + v) * SS + m0;
        float* op1 = khop_ws + (((size_t)(bb + 128) * NHH + h) * SS + v) * SS + m0;
        if (m0 + 3 <= v) {
            *reinterpret_cast<float4*>(op0) = make_float4(a0[g*4+0], a0[g*4+1], a0[g*4+2], a0[g*4+3]);
            *reinterpret_cast<float4*>(op1) = make_float4(a1[g*4+0], a1[g*4+1], a1[g*4+2], a1[g*4+3]);
        } else {
            #pragma unroll
            for (int mm = 0; mm < 4; ++mm) {
                if (m0 + mm <= v) { op0[mm] = a0[g*4+mm]; op1[mm] = a1[g*4+mm]; }
            }
        }
    }
}

// ---------------------------------------------------------------------------
// Kernel 3: SPLIT-PRECISION MFMA QK^T (hi/lo bf16, 3 passes -> ~2^-18 fidelity)
// + r2-PROVEN C-phase/PV/LayerNorm. khop f32 (proven path).
// ---------------------------------------------------------------------------
__global__ __launch_bounds__(256) void k_attn(
    const float* __restrict__ q, const float* __restrict__ k, const float* __restrict__ v,
    const float* __restrict__ lnw, const float* __restrict__ lnb,
    const float* __restrict__ ig_ws, const float* __restrict__ csum_ws,
    const float* __restrict__ pmax_ws, const float* __restrict__ khop_ws,
    float* __restrict__ out)
{
    __shared__ __attribute__((aligned(16))) unsigned short Kspl[2 * 64 * 136]; // Khi|Klo; reused as hsb f32[64][132]
    __shared__ float cs[SS][68];        // khop preload -> S+khop -> C
    __shared__ float csum_s[65];
    __shared__ float ig_s[64];
    __shared__ float pmax_s[64];
    __shared__ float invr[64];

    const int bid = blockIdx.x;
    const int b = bid >> 3, h = bid & 7;
    const int t = threadIdx.x;
    const int w = t >> 6, l = t & 63, c = l & 15, g = l >> 4;
    const float rs_dh = 0.08838834764831845f;  // 1/sqrt(128)

    unsigned short* Khi = Kspl;               // [64][136]
    unsigned short* Klo = Kspl + 64 * 136;    // [64][136]

    // ---- stage K as hi/lo split bf16 (scaled by 1/sqrt(DH) BEFORE split) ----
    #pragma unroll
    for (int it = 0; it < 2; ++it) {
        const int u = t + 256 * it;
        const int row = u >> 3, seg = u & 7;
        const float* kp = k + ((size_t)(b * 64 + row)) * 1024 + h * 128;
        #pragma unroll
        for (int e = 0; e < 2; ++e) {
            const int col = e * 64 + seg * 8;
            const float4 ya = *reinterpret_cast<const float4*>(kp + col);
            const float4 yb = *reinterpret_cast<const float4*>(kp + col + 4);
            unsigned* dh = reinterpret_cast<unsigned*>(&Khi[row * 136 + col]);
            unsigned* dl = reinterpret_cast<unsigned*>(&Klo[row * 136 + col]);
            split2(ya.x * rs_dh, ya.y * rs_dh, dh[0], dl[0]);
            split2(ya.z * rs_dh, ya.w * rs_dh, dh[1], dl[1]);
            split2(yb.x * rs_dh, yb.y * rs_dh, dh[2], dl[2]);
            split2(yb.z * rs_dh, yb.w * rs_dh, dh[3], dl[3]);
        }
    }
    // ---- stage khop f32 into cs (r2-proven pattern) ----
    {
        const float* khb = khop_ws + (b * NHH + h) * SS * SS;
        for (int idx = t; idx < SS * 16; idx += 256) {
            const int row = idx >> 4, j4 = idx & 15;
            *reinterpret_cast<float4*>(&cs[row][j4 * 4]) =
                *reinterpret_cast<const float4*>(khb + row * SS + j4 * 4);
        }
    }
    const int cb = b * NHH + h;
    if (t < 65) csum_s[t] = csum_ws[cb * 65 + t];
    if (t >= 128 && t < 192) ig_s[t - 128] = ig_ws[cb * SS + (t - 128)];
    if (t >= 192) pmax_s[t - 192] = pmax_ws[cb * SS + (t - 192)];

    // ---- Q A-frags from global, split hi/lo in registers (lane-exact reads) ----
    union bfu { unsigned u[4]; bf16x8 v; };
    bfu qhi[4], qlo[4];
    {
        const int qrow = 16 * w + c;
        const float* qbase = q + ((size_t)(b * 64 + qrow)) * 1024 + h * 128 + 8 * g;
        #pragma unroll
        for (int kk = 0; kk < 4; ++kk) {
            const float4 f0 = *reinterpret_cast<const float4*>(qbase + 32 * kk);
            const float4 f1 = *reinterpret_cast<const float4*>(qbase + 32 * kk + 4);
            split2(f0.x, f0.y, qhi[kk].u[0], qlo[kk].u[0]);
            split2(f0.z, f0.w, qhi[kk].u[1], qlo[kk].u[1]);
            split2(f1.x, f1.y, qhi[kk].u[2], qlo[kk].u[2]);
            split2(f1.z, f1.w, qhi[kk].u[3], qlo[kk].u[3]);
        }
    }
    __syncthreads();

    // ---- QK^T via 3-pass split MFMA: S = Qhi*Khi + Qlo*Khi + Qhi*Klo ----
    {
        f32x4 acc[4];
        #pragma unroll
        for (int n = 0; n < 4; ++n) { acc[n][0]=0.f; acc[n][1]=0.f; acc[n][2]=0.f; acc[n][3]=0.f; }
        #pragma unroll
        for (int kk = 0; kk < 4; ++kk) {
            #pragma unroll
            for (int n = 0; n < 4; ++n) {
                const int off = (16 * n + c) * 136 + 32 * kk + 8 * g;
                bf16x8 bhi = *reinterpret_cast<const bf16x8*>(&Khi[off]);
                bf16x8 blo = *reinterpret_cast<const bf16x8*>(&Klo[off]);
                acc[n] = __builtin_amdgcn_mfma_f32_16x16x32_bf16(qhi[kk].v, bhi, acc[n], 0, 0, 0);
                acc[n] = __builtin_amdgcn_mfma_f32_16x16x32_bf16(qlo[kk].v, bhi, acc[n], 0, 0, 0);
                acc[n] = __builtin_amdgcn_mfma_f32_16x16x32_bf16(qhi[kk].v, blo, acc[n], 0, 0, 0);
            }
        }
        // scatter-add S into cs (each (i,j) owned by exactly one lane)
        #pragma unroll
        for (int n = 0; n < 4; ++n) {
            const int j = 16 * n + c;
            #pragma unroll
            for (int reg = 0; reg < 4; ++reg) {
                const int i = 16 * w + 4 * g + reg;
                cs[i][j] += acc[n][reg];
            }
        }
    }
    __syncthreads();

    // ---- C phase (r2-proven formulas) ----
    const int i = t >> 2, qq = t & 3;
    const float m_i = csum_s[i + 1] + pmax_s[i];
    float rs = 0.0f;
    for (int j = qq; j <= i; j += 4) {
        const float sc = cs[i][j];
        const float logD = csum_s[i + 1] - csum_s[j + 1] + ig_s[j];
        const float C = sc * __expf(logD - m_i);
        rs += C;
        cs[i][j] = C;
    }
    for (int j = i + 1 + ((qq - (i + 1)) & 3); j < SS; j += 4) cs[i][j] = 0.0f;
    rs += __shfl_xor(rs, 1, 64);
    rs += __shfl_xor(rs, 2, 64);
    const float nrm = fmaxf(fabsf(rs), __expf(-m_i));
    if (qq == 0) invr[i] = 1.0f / (nrm + 1e-6f);
    __syncthreads();

    // ---- PV (r2-proven verbatim; hsb aliases dead K tiles) ----
    const int g2 = t >> 7, c2 = t & 127;
    float acc[32];
    #pragma unroll
    for (int r = 0; r < 32; ++r) acc[r] = 0.0f;
    const int j4max = (g2 == 0) ? 8 : 16;
    const float* vb = v + (b * SS) * DIMM + h * DHH + c2;
    for (int j4 = 0; j4 < j4max; ++j4) {
        const float v0 = vb[(j4 * 4 + 0) * DIMM];
        const float v1 = vb[(j4 * 4 + 1) * DIMM];
        const float v2 = vb[(j4 * 4 + 2) * DIMM];
        const float v3 = vb[(j4 * 4 + 3) * DIMM];
        #pragma unroll
        for (int r = 0; r < 32; ++r) {
            const float4 cw = *reinterpret_cast<const float4*>(&cs[g2 * 32 + r][j4 * 4]);
            acc[r] = fmaf(cw.x, v0, fmaf(cw.y, v1, fmaf(cw.z, v2, fmaf(cw.w, v3, acc[r]))));
        }
    }
    float* hsb = reinterpret_cast<float*>(Kspl);  // [64][132]
    #pragma unroll
    for (int r = 0; r < 32; ++r) {
        const int row = g2 * 32 + r;
        hsb[row * 132 + c2] = acc[r] * invr[row];
    }
    __syncthreads();

    // ---- fused per-head LayerNorm + output (r2-proven verbatim) ----
    {
        float vals[32];
        float sum = 0.f, sq = 0.f;
        #pragma unroll
        for (int e = 0; e < 8; ++e) {
            const float4 x = *reinterpret_cast<const float4*>(&hsb[i * 132 + qq * 32 + e * 4]);
            vals[e*4+0] = x.x; vals[e*4+1] = x.y; vals[e*4+2] = x.z; vals[e*4+3] = x.w;
            sum += x.x + x.y + x.z + x.w;
            sq = fmaf(x.x, x.x, fmaf(x.y, x.y, fmaf(x.z, x.z, fmaf(x.w, x.w, sq))));
        }
        sum += __shfl_xor(sum, 1, 64); sum += __shfl_xor(sum, 2, 64);
        sq  += __shfl_xor(sq, 1, 64);  sq  += __shfl_xor(sq, 2, 64);
        const float mu = sum * (1.0f / 128.0f);
        const float var = sq * (1.0f / 128.0f) - mu * mu;
        const float rstd = rsqrtf(var + 1e-5f);
        float* op = out + ((b * SS + i) * NHH + h) * DHH + qq * 32;
        const float* wp = lnw + h * DHH + qq * 32;
        const float* bp = lnb + h * DHH + qq * 32;
        #pragma unroll
        for (int e = 0; e < 8; ++e) {
            float4 o;
            o.x = (vals[e*4+0] - mu) * rstd * (1.0f + wp[e*4+0]) + bp[e*4+0];
            o.y = (vals[e*4+1] - mu) * rstd * (1.0f + wp[e*4+1]) + bp[e*4+1];
            o.z = (vals[e*4+2] - mu) * rstd * (1.0f + wp[e*4+2]) + bp[e*4+2];
            o.w = (vals[e*4+3] - mu) * rstd * (1.0f + wp[e*4+3]) + bp[e*4+3];
            *reinterpret_cast<float4*>(op + e * 4) = o;
        }
    }
}

extern "C" void kernel_launch(void* const* d_in, const int* in_sizes, int n_in,
                              void* d_out, int out_size, void* d_ws, size_t ws_size,
                              hipStream_t stream) {
    const float* q   = (const float*)d_in[0];
    const float* k   = (const float*)d_in[1];
    const float* v   = (const float*)d_in[2];
    const float* igw = (const float*)d_in[3];
    const float* igb = (const float*)d_in[4];
    const float* fgw = (const float*)d_in[5];
    const float* fgb = (const float*)d_in[6];
    const float* rpe = (const float*)d_in[7];
    const float* lnw = (const float*)d_in[8];
    const float* lnb = (const float*)d_in[9];
    const int*  hops = (const int*)d_in[10];
    float* out = (float*)d_out;

    // ws (floats): ig[131072] | pmax[131072] | csum[133120] | REGION (aliased):
    //   gate-MFMA partials (1.05M f32) consumed by k_gates_final BEFORE k_khop
    //   overwrites the region as khop_ws (8.39M f32). Same-stream ordering.
    float* ig_ws   = (float*)d_ws;
    float* pmax_ws = ig_ws + 131072;
    float* csum_ws = pmax_ws + 131072;
    float* part    = csum_ws + 133120;
    float* khop_ws = part;

    hipLaunchKernelGGL(k_gate_mfma, dim3(1024), dim3(256), 0, stream,
                       q, k, v, igw, fgw, part);
    hipLaunchKernelGGL(k_gates_final, dim3(BB), dim3(256), 0, stream,
                       part, igb, fgb, ig_ws, csum_ws, pmax_ws);
    hipLaunchKernelGGL(k_khop, dim3(SS, NHH), dim3(512), 0, stream,
                       q, rpe, hops, khop_ws);
    hipLaunchKernelGGL(k_attn, dim3(BB * NHH), dim3(256), 0, stream,
                       q, k, v, lnw, lnb, ig_ws, csum_ws, pmax_ws, khop_ws, out);
}

// Round 10
// 228.173 us; speedup vs baseline: 2.5017x; 1.2249x over previous
//
#include <hip/hip_runtime.h>
#include <math.h>

#define BB 256
#define SS 64
#define DIMM 1024
#define NHH 8
#define DHH 128

typedef short bf16x8 __attribute__((ext_vector_type(8)));
typedef float f32x4 __attribute__((ext_vector_type(4)));

__device__ __forceinline__ unsigned f2bf(float f) {   // bf16 bits (RNE) in low 16
    union { float f; unsigned u; } x{f};
    return (x.u + 0x7FFFu + ((x.u >> 16) & 1u)) >> 16;
}
__device__ __forceinline__ unsigned pk2(float lo, float hi) {
    return f2bf(lo) | (f2bf(hi) << 16);
}
__device__ __forceinline__ float bf2f(unsigned short b) {
    union { unsigned u; float f; } x{((unsigned)b) << 16};
    return x.f;
}
// split a,b into hi-bf16 pair and residual-lo-bf16 pair (packed words)
__device__ __forceinline__ void split2(float a, float b, unsigned& hi, unsigned& lo) {
    const unsigned ha = f2bf(a), hb = f2bf(b);
    hi = ha | (hb << 16);
    lo = pk2(a - bf2f((unsigned short)ha), b - bf2f((unsigned short)hb));
}
__device__ __forceinline__ float logsigf(float x) {
    return fminf(x, 0.0f) - log1pf(__expf(-fabsf(x)));
}

// ---------------------------------------------------------------------------
// Kernel 1a (r6-PROVEN): gate GEMM partials via MFMA.
// ---------------------------------------------------------------------------
__global__ __launch_bounds__(256) void k_gate_mfma(
    const float* __restrict__ q, const float* __restrict__ k, const float* __restrict__ v,
    const float* __restrict__ igw, const float* __restrict__ fgw,
    float* __restrict__ part)
{
    __shared__ unsigned short Xs[64 * 264];   // [64][256+8] bf16
    __shared__ unsigned short Ws[16 * 264];
    const int b = blockIdx.x & 255;
    const int ksl = blockIdx.x >> 8;
    const int t = threadIdx.x;
    const int w = t >> 6, l = t & 63, c = l & 15, g = l >> 4;

    f32x4 acc;
    acc[0] = 0.f; acc[1] = 0.f; acc[2] = 0.f; acc[3] = 0.f;

    for (int step = 0; step < 3; ++step) {
        const int kc = ksl * 3 + step;
        const int tensor = kc >> 2;
        const float* src = (tensor == 0) ? q : (tensor == 1) ? k : v;
        src += ((size_t)b * 64) * 1024 + (kc & 3) * 256;
        {
            const int row = t >> 2, seg = t & 3;
            const float* rp = src + row * 1024;
            #pragma unroll
            for (int e = 0; e < 16; ++e) {
                const int col = e * 16 + seg * 4;
                const float4 x = *reinterpret_cast<const float4*>(rp + col);
                unsigned* dp = reinterpret_cast<unsigned*>(&Xs[row * 264 + col]);
                dp[0] = pk2(x.x, x.y); dp[1] = pk2(x.z, x.w);
            }
        }
        {
            const int o = t >> 4, wseg = t & 15;
            const int p0 = ksl * 768 + step * 256;
            const float* wp = (o < 8 ? igw + o * 3072 : fgw + (o - 8) * 3072) + p0;
            #pragma unroll
            for (int e = 0; e < 4; ++e) {
                const int col = e * 64 + wseg * 4;
                const float4 x = *reinterpret_cast<const float4*>(wp + col);
                unsigned* dp = reinterpret_cast<unsigned*>(&Ws[o * 264 + col]);
                dp[0] = pk2(x.x, x.y); dp[1] = pk2(x.z, x.w);
            }
        }
        __syncthreads();
        #pragma unroll
        for (int kk = 0; kk < 8; ++kk) {
            bf16x8 a  = *reinterpret_cast<const bf16x8*>(&Xs[(16 * w + c) * 264 + 32 * kk + 8 * g]);
            bf16x8 bw = *reinterpret_cast<const bf16x8*>(&Ws[c * 264 + 32 * kk + 8 * g]);
            acc = __builtin_amdgcn_mfma_f32_16x16x32_bf16(a, bw, acc, 0, 0, 0);
        }
        __syncthreads();
    }
    float* pb = part + (((size_t)ksl * 256 + b) * 64) * 16;
    #pragma unroll
    for (int reg = 0; reg < 4; ++reg) {
        const int s = 16 * w + 4 * g + reg;
        pb[s * 16 + c] = acc[reg];
    }
}

// ---------------------------------------------------------------------------
// Kernel 1b (r6-PROVEN): reduce partials + bias, log-sigmoid, cumsum, pmax.
// ---------------------------------------------------------------------------
__global__ __launch_bounds__(256) void k_gates_final(
    const float* __restrict__ part, const float* __restrict__ igb, const float* __restrict__ fgb,
    float* __restrict__ ig_ws, float* __restrict__ csum_ws, float* __restrict__ pmax_ws)
{
    const int b = blockIdx.x;
    const int t = threadIdx.x;
    __shared__ float red[64][18];
    {
        const int s = t >> 2, oq = t & 3;
        float4 sum = make_float4(0.f, 0.f, 0.f, 0.f);
        #pragma unroll
        for (int ksl = 0; ksl < 4; ++ksl) {
            const float4 p = *reinterpret_cast<const float4*>(
                part + (((size_t)ksl * 256 + b) * 64 + s) * 16 + oq * 4);
            sum.x += p.x; sum.y += p.y; sum.z += p.z; sum.w += p.w;
        }
        red[s][oq * 4 + 0] = sum.x; red[s][oq * 4 + 1] = sum.y;
        red[s][oq * 4 + 2] = sum.z; red[s][oq * 4 + 3] = sum.w;
    }
    __syncthreads();
    if (t < 64) {
        const int s = t;
        #pragma unroll
        for (int h = 0; h < 8; ++h) {
            float ig = red[s][h]     + igb[h];
            float fg = red[s][8 + h] + fgb[h];
            float lf = logsigf(fg);
            float cs = lf;
            #pragma unroll
            for (int d = 1; d < 64; d <<= 1) {
                float o = __shfl_up(cs, (unsigned)d, 64);
                if (s >= d) cs += o;
            }
            float pm = ig - cs;
            #pragma unroll
            for (int d = 1; d < 64; d <<= 1) {
                float o = __shfl_up(pm, (unsigned)d, 64);
                if (s >= d) pm = fmaxf(pm, o);
            }
            const int base = b * NHH + h;
            ig_ws[base * SS + s] = ig;
            csum_ws[base * 65 + s + 1] = cs;
            if (s == 0) csum_ws[base * 65] = 0.0f;
            pmax_ws[base * SS + s] = pm;
        }
    }
}

// ---------------------------------------------------------------------------
// Kernel 2 (r6-PROVEN): khop[b][h][v][m] f32.
// ---------------------------------------------------------------------------
__global__ __launch_bounds__(512) void k_khop(
    const float* __restrict__ q, const float* __restrict__ rpe, const int* __restrict__ hops,
    float* __restrict__ khop_ws)
{
    const int v = blockIdx.x;
    const int h = blockIdx.y;
    const int t = threadIdx.x;
    __shared__ float pe[SS][132];
    const int nelem = (v + 1) * DHH;
    for (int idx = t; idx < nelem; idx += 512) {
        const int m = idx >> 7, cc = idx & 127;
        pe[m][cc] = rpe[hops[v * SS + m] * DIMM + h * DHH + cc];
    }
    __syncthreads();

    const int bb = t & 127;
    const int mq = t >> 7;
    float a0[16], a1[16];
    #pragma unroll
    for (int e = 0; e < 16; ++e) { a0[e] = 0.0f; a1[e] = 0.0f; }
    const float* q0 = q + ((size_t)(bb)       * SS + v) * DIMM + h * DHH;
    const float* q1 = q + ((size_t)(bb + 128) * SS + v) * DIMM + h * DHH;

    #pragma unroll
    for (int c0 = 0; c0 < 4; ++c0) {
        float4 qa[8], qb[8];
        #pragma unroll
        for (int e = 0; e < 8; ++e) {
            qa[e] = *reinterpret_cast<const float4*>(q0 + c0 * 32 + e * 4);
            qb[e] = *reinterpret_cast<const float4*>(q1 + c0 * 32 + e * 4);
        }
        #pragma unroll
        for (int g = 0; g < 4; ++g) {
            const int m0 = (mq + g * 4) * 4;
            if (m0 > v) continue;
            #pragma unroll
            for (int mm = 0; mm < 4; ++mm) {
                float s0 = 0.0f, s1 = 0.0f;
                #pragma unroll
                for (int e = 0; e < 8; ++e) {
                    const float4 p4 = *reinterpret_cast<const float4*>(&pe[m0 + mm][c0 * 32 + e * 4]);
                    s0 = fmaf(qa[e].x, p4.x, fmaf(qa[e].y, p4.y, fmaf(qa[e].z, p4.z, fmaf(qa[e].w, p4.w, s0))));
                    s1 = fmaf(qb[e].x, p4.x, fmaf(qb[e].y, p4.y, fmaf(qb[e].z, p4.z, fmaf(qb[e].w, p4.w, s1))));
                }
                a0[g * 4 + mm] += s0;
                a1[g * 4 + mm] += s1;
            }
        }
    }
    #pragma unroll
    for (int g = 0; g < 4; ++g) {
        const int m0 = (mq + g * 4) * 4;
        if (m0 > v) continue;
        float* op0 = khop_ws + (((size_t)bb         * NHH + h) * SS + v) * SS + m0;
        float* op1 = khop_ws + (((size_t)(bb + 128) * NHH + h) * SS + v) * SS + m0;
        if (m0 + 3 <= v) {
            *reinterpret_cast<float4*>(op0) = make_float4(a0[g*4+0], a0[g*4+1], a0[g*4+2], a0[g*4+3]);
            *reinterpret_cast<float4*>(op1) = make_float4(a1[g*4+0], a1[g*4+1], a1[g*4+2], a1[g*4+3]);
        } else {
            #pragma unroll
            for (int mm = 0; mm < 4; ++mm) {
                if (m0 + mm <= v) { op0[mm] = a0[g*4+mm]; op1[mm] = a1[g*4+mm]; }
            }
        }
    }
}

// ---------------------------------------------------------------------------
// Kernel 3: split-precision MFMA QK^T (r9-PROVEN) + f32 C-phase (r9-PROVEN)
// + NEW: bf16 Cn + V^T-swizzled MFMA PV + in-register LayerNorm (r7 epilogue,
// exonerated by the sign-cliff post-mortem). V^T reuses the dead Khi/Klo LDS.
// ---------------------------------------------------------------------------
__global__ __launch_bounds__(256) void k_attn(
    const float* __restrict__ q, const float* __restrict__ k, const float* __restrict__ v,
    const float* __restrict__ lnw, const float* __restrict__ lnb,
    const float* __restrict__ ig_ws, const float* __restrict__ csum_ws,
    const float* __restrict__ pmax_ws, const float* __restrict__ khop_ws,
    float* __restrict__ out)
{
    __shared__ __attribute__((aligned(16))) unsigned short Kspl[2 * 64 * 136]; // Khi|Klo -> VT(9216)+Cn(4608) shorts
    __shared__ float cs[SS][68];        // khop preload -> S+khop -> C
    __shared__ float csum_s[65];
    __shared__ float ig_s[64];
    __shared__ float pmax_s[64];
    __shared__ float invr[64];
    __shared__ float lnw_s[128];
    __shared__ float lnb_s[128];

    const int bid = blockIdx.x;
    const int b = bid >> 3, h = bid & 7;
    const int t = threadIdx.x;
    const int w = t >> 6, l = t & 63, c = l & 15, g = l >> 4;
    const float rs_dh = 0.08838834764831845f;  // 1/sqrt(128)

    unsigned short* Khi = Kspl;               // [64][136]
    unsigned short* Klo = Kspl + 64 * 136;    // [64][136]

    // ---- issue V loads into registers early (written to VT after QK^T) ----
    float4 vreg[2][4];
    #pragma unroll
    for (int it = 0; it < 2; ++it) {
        const int u = t + 256 * it;
        const int jp = u >> 4, seg8 = u & 15;
        const float* r0 = v + ((size_t)(b * 64 + 2 * jp)) * 1024 + h * 128 + seg8 * 8;
        vreg[it][0] = *reinterpret_cast<const float4*>(r0);
        vreg[it][1] = *reinterpret_cast<const float4*>(r0 + 4);
        vreg[it][2] = *reinterpret_cast<const float4*>(r0 + 1024);
        vreg[it][3] = *reinterpret_cast<const float4*>(r0 + 1028);
    }

    // ---- stage K as hi/lo split bf16 (scaled by 1/sqrt(DH) BEFORE split) ----
    #pragma unroll
    for (int it = 0; it < 2; ++it) {
        const int u = t + 256 * it;
        const int row = u >> 3, seg = u & 7;
        const float* kp = k + ((size_t)(b * 64 + row)) * 1024 + h * 128;
        #pragma unroll
        for (int e = 0; e < 2; ++e) {
            const int col = e * 64 + seg * 8;
            const float4 ya = *reinterpret_cast<const float4*>(kp + col);
            const float4 yb = *reinterpret_cast<const float4*>(kp + col + 4);
            unsigned* dh = reinterpret_cast<unsigned*>(&Khi[row * 136 + col]);
            unsigned* dl = reinterpret_cast<unsigned*>(&Klo[row * 136 + col]);
            split2(ya.x * rs_dh, ya.y * rs_dh, dh[0], dl[0]);
            split2(ya.z * rs_dh, ya.w * rs_dh, dh[1], dl[1]);
            split2(yb.x * rs_dh, yb.y * rs_dh, dh[2], dl[2]);
            split2(yb.z * rs_dh, yb.w * rs_dh, dh[3], dl[3]);
        }
    }
    // ---- stage khop f32 into cs (r2-proven pattern) ----
    {
        const float* khb = khop_ws + (b * NHH + h) * SS * SS;
        for (int idx = t; idx < SS * 16; idx += 256) {
            const int row = idx >> 4, j4 = idx & 15;
            *reinterpret_cast<float4*>(&cs[row][j4 * 4]) =
                *reinterpret_cast<const float4*>(khb + row * SS + j4 * 4);
        }
    }
    const int cb = b * NHH + h;
    if (t < 65) csum_s[t] = csum_ws[cb * 65 + t];
    if (t >= 128 && t < 192) ig_s[t - 128] = ig_ws[cb * SS + (t - 128)];
    if (t >= 192) pmax_s[t - 192] = pmax_ws[cb * SS + (t - 192)];
    if (t < 128) lnw_s[t] = lnw[h * 128 + t];
    else if (t < 256) lnb_s[t - 128] = lnb[h * 128 + (t - 128)];

    // ---- Q A-frags from global, split hi/lo in registers (lane-exact reads) ----
    union bfu { unsigned u[4]; bf16x8 v; };
    bfu qhi[4], qlo[4];
    {
        const int qrow = 16 * w + c;
        const float* qbase = q + ((size_t)(b * 64 + qrow)) * 1024 + h * 128 + 8 * g;
        #pragma unroll
        for (int kk = 0; kk < 4; ++kk) {
            const float4 f0 = *reinterpret_cast<const float4*>(qbase + 32 * kk);
            const float4 f1 = *reinterpret_cast<const float4*>(qbase + 32 * kk + 4);
            split2(f0.x, f0.y, qhi[kk].u[0], qlo[kk].u[0]);
            split2(f0.z, f0.w, qhi[kk].u[1], qlo[kk].u[1]);
            split2(f1.x, f1.y, qhi[kk].u[2], qlo[kk].u[2]);
            split2(f1.z, f1.w, qhi[kk].u[3], qlo[kk].u[3]);
        }
    }
    __syncthreads();

    // ---- QK^T via 3-pass split MFMA: S = Qhi*Khi + Qlo*Khi + Qhi*Klo ----
    {
        f32x4 acc[4];
        #pragma unroll
        for (int n = 0; n < 4; ++n) { acc[n][0]=0.f; acc[n][1]=0.f; acc[n][2]=0.f; acc[n][3]=0.f; }
        #pragma unroll
        for (int kk = 0; kk < 4; ++kk) {
            #pragma unroll
            for (int n = 0; n < 4; ++n) {
                const int off = (16 * n + c) * 136 + 32 * kk + 8 * g;
                bf16x8 bhi = *reinterpret_cast<const bf16x8*>(&Khi[off]);
                bf16x8 blo = *reinterpret_cast<const bf16x8*>(&Klo[off]);
                acc[n] = __builtin_amdgcn_mfma_f32_16x16x32_bf16(qhi[kk].v, bhi, acc[n], 0, 0, 0);
                acc[n] = __builtin_amdgcn_mfma_f32_16x16x32_bf16(qlo[kk].v, bhi, acc[n], 0, 0, 0);
                acc[n] = __builtin_amdgcn_mfma_f32_16x16x32_bf16(qhi[kk].v, blo, acc[n], 0, 0, 0);
            }
        }
        #pragma unroll
        for (int n = 0; n < 4; ++n) {
            const int j = 16 * n + c;
            #pragma unroll
            for (int reg = 0; reg < 4; ++reg) {
                const int i = 16 * w + 4 * g + reg;
                cs[i][j] += acc[n][reg];
            }
        }
    }
    __syncthreads();   // Khi/Klo now dead; S complete in cs

    // ---- write V^T (bf16, XOR-swizzled) into dead K region ----
    unsigned short* VT = Kspl;                 // [128 rows][72 shorts] region, swizzled bytes
    unsigned short* Cn = Kspl + 128 * 72;      // [64][72] bf16
    #pragma unroll
    for (int it = 0; it < 2; ++it) {
        const int u = t + 256 * it;
        const int jp = u >> 4, seg8 = u & 15;
        float v0[8], v1[8];
        v0[0]=vreg[it][0].x; v0[1]=vreg[it][0].y; v0[2]=vreg[it][0].z; v0[3]=vreg[it][0].w;
        v0[4]=vreg[it][1].x; v0[5]=vreg[it][1].y; v0[6]=vreg[it][1].z; v0[7]=vreg[it][1].w;
        v1[0]=vreg[it][2].x; v1[1]=vreg[it][2].y; v1[2]=vreg[it][2].z; v1[3]=vreg[it][2].w;
        v1[4]=vreg[it][3].x; v1[5]=vreg[it][3].y; v1[6]=vreg[it][3].z; v1[7]=vreg[it][3].w;
        #pragma unroll
        for (int m = 0; m < 8; ++m) {
            const int cc = seg8 * 8 + m;
            unsigned byte = (unsigned)(cc * 144 + 4 * jp);
            byte ^= ((cc >> 3) & 7) << 4;
            *reinterpret_cast<unsigned*>(reinterpret_cast<char*>(VT) + byte) = pk2(v0[m], v1[m]);
        }
    }

    // ---- C phase (r9-proven formulas) ----
    const int i = t >> 2, qq = t & 3;
    {
        const float m_i = csum_s[i + 1] + pmax_s[i];
        float rs = 0.0f;
        for (int j = qq; j <= i; j += 4) {
            const float sc = cs[i][j];
            const float logD = csum_s[i + 1] - csum_s[j + 1] + ig_s[j];
            const float C = sc * __expf(logD - m_i);
            rs += C;
            cs[i][j] = C;
        }
        for (int j = i + 1 + ((qq - (i + 1)) & 3); j < SS; j += 4) cs[i][j] = 0.0f;
        rs += __shfl_xor(rs, 1, 64);
        rs += __shfl_xor(rs, 2, 64);
        const float nrm = fmaxf(fabsf(rs), __expf(-m_i));
        if (qq == 0) invr[i] = 1.0f / (nrm + 1e-6f);
    }
    __syncthreads();

    // ---- convert C -> bf16 Cn (x invr) ----
    {
        const int row = t >> 2, qtr = t & 3;
        const float ir = invr[row];
        unsigned* dp = reinterpret_cast<unsigned*>(&Cn[row * 72 + qtr * 16]);
        #pragma unroll
        for (int e = 0; e < 4; ++e) {
            const float4 x = *reinterpret_cast<const float4*>(&cs[row][qtr * 16 + e * 4]);
            dp[e * 2 + 0] = pk2(x.x * ir, x.y * ir);
            dp[e * 2 + 1] = pk2(x.z * ir, x.w * ir);
        }
    }
    __syncthreads();

    // ---- PV via MFMA: H[16-row strip][128] per wave ----
    f32x4 hacc[8];
    #pragma unroll
    for (int n = 0; n < 8; ++n) { hacc[n][0]=0.f; hacc[n][1]=0.f; hacc[n][2]=0.f; hacc[n][3]=0.f; }
    #pragma unroll
    for (int ks = 0; ks < 2; ++ks) {
        bf16x8 a = *reinterpret_cast<const bf16x8*>(&Cn[(16 * w + c) * 72 + 32 * ks + 8 * g]);
        #pragma unroll
        for (int n = 0; n < 8; ++n) {
            const int cc = 16 * n + c;
            unsigned byte = (unsigned)(cc * 144 + 64 * ks + 16 * g);
            byte ^= ((cc >> 3) & 7) << 4;
            bf16x8 bv = *reinterpret_cast<const bf16x8*>(reinterpret_cast<const char*>(VT) + byte);
            hacc[n] = __builtin_amdgcn_mfma_f32_16x16x32_bf16(a, bv, hacc[n], 0, 0, 0);
        }
    }

    // ---- fused per-head LayerNorm + output (in fragment registers) ----
    #pragma unroll
    for (int reg = 0; reg < 4; ++reg) {
        float s1 = 0.f, s2 = 0.f;
        #pragma unroll
        for (int n = 0; n < 8; ++n) { const float x = hacc[n][reg]; s1 += x; s2 = fmaf(x, x, s2); }
        s1 += __shfl_xor(s1, 1); s1 += __shfl_xor(s1, 2);
        s1 += __shfl_xor(s1, 4); s1 += __shfl_xor(s1, 8);
        s2 += __shfl_xor(s2, 1); s2 += __shfl_xor(s2, 2);
        s2 += __shfl_xor(s2, 4); s2 += __shfl_xor(s2, 8);
        const float mu = s1 * (1.0f / 128.0f);
        const float var = s2 * (1.0f / 128.0f) - mu * mu;
        const float rstd = rsqrtf(var + 1e-5f);
        const int io = 16 * w + 4 * g + reg;
        float* op = out + (((size_t)(b * 64 + io)) * 8 + h) * 128;
        #pragma unroll
        for (int n = 0; n < 8; ++n) {
            const int cc = 16 * n + c;
            op[cc] = (hacc[n][reg] - mu) * rstd * (1.0f + lnw_s[cc]) + lnb_s[cc];
        }
    }
}

extern "C" void kernel_launch(void* const* d_in, const int* in_sizes, int n_in,
                              void* d_out, int out_size, void* d_ws, size_t ws_size,
                              hipStream_t stream) {
    const float* q   = (const float*)d_in[0];
    const float* k   = (const float*)d_in[1];
    const float* v   = (const float*)d_in[2];
    const float* igw = (const float*)d_in[3];
    const float* igb = (const float*)d_in[4];
    const float* fgw = (const float*)d_in[5];
    const float* fgb = (const float*)d_in[6];
    const float* rpe = (const float*)d_in[7];
    const float* lnw = (const float*)d_in[8];
    const float* lnb = (const float*)d_in[9];
    const int*  hops = (const int*)d_in[10];
    float* out = (float*)d_out;

    // ws (floats): ig[131072] | pmax[131072] | csum[133120] | REGION (aliased):
    //   gate-MFMA partials (1.05M f32) consumed by k_gates_final BEFORE k_khop
    //   overwrites the region as khop_ws (8.39M f32). Same-stream ordering.
    float* ig_ws   = (float*)d_ws;
    float* pmax_ws = ig_ws + 131072;
    float* csum_ws = pmax_ws + 131072;
    float* part    = csum_ws + 133120;
    float* khop_ws = part;

    hipLaunchKernelGGL(k_gate_mfma, dim3(1024), dim3(256), 0, stream,
                       q, k, v, igw, fgw, part);
    hipLaunchKernelGGL(k_gates_final, dim3(BB), dim3(256), 0, stream,
                       part, igb, fgb, ig_ws, csum_ws, pmax_ws);
    hipLaunchKernelGGL(k_khop, dim3(SS, NHH), dim3(512), 0, stream,
                       q, rpe, hops, khop_ws);
    hipLaunchKernelGGL(k_attn, dim3(BB * NHH), dim3(256), 0, stream,
                       q, k, v, lnw, lnb, ig_ws, csum_ws, pmax_ws, khop_ws, out);
}

// Round 11
// 134.989 us; speedup vs baseline: 4.2287x; 1.6903x over previous
//
#include <hip/hip_runtime.h>
#include <math.h>

#define BB 256
#define SS 64
#define DIMM 1024
#define NHH 8
#define DHH 128

typedef short bf16x8 __attribute__((ext_vector_type(8)));
typedef float f32x4 __attribute__((ext_vector_type(4)));

__device__ __forceinline__ unsigned f2bf(float f) {   // bf16 bits (RNE) in low 16
    union { float f; unsigned u; } x{f};
    return (x.u + 0x7FFFu + ((x.u >> 16) & 1u)) >> 16;
}
__device__ __forceinline__ unsigned pk2(float lo, float hi) {
    return f2bf(lo) | (f2bf(hi) << 16);
}
__device__ __forceinline__ float bf2f(unsigned short b) {
    union { unsigned u; float f; } x{((unsigned)b) << 16};
    return x.f;
}
// split a,b into hi-bf16 pair and residual-lo-bf16 pair (packed words)
__device__ __forceinline__ void split2(float a, float b, unsigned& hi, unsigned& lo) {
    const unsigned ha = f2bf(a), hb = f2bf(b);
    hi = ha | (hb << 16);
    lo = pk2(a - bf2f((unsigned short)ha), b - bf2f((unsigned short)hb));
}
__device__ __forceinline__ float logsigf(float x) {
    return fminf(x, 0.0f) - log1pf(__expf(-fabsf(x)));
}

// ---------------------------------------------------------------------------
// Kernel 1a (r6-PROVEN): gate GEMM partials via MFMA.
// ---------------------------------------------------------------------------
__global__ __launch_bounds__(256) void k_gate_mfma(
    const float* __restrict__ q, const float* __restrict__ k, const float* __restrict__ v,
    const float* __restrict__ igw, const float* __restrict__ fgw,
    float* __restrict__ part)
{
    __shared__ unsigned short Xs[64 * 264];   // [64][256+8] bf16
    __shared__ unsigned short Ws[16 * 264];
    const int b = blockIdx.x & 255;
    const int ksl = blockIdx.x >> 8;
    const int t = threadIdx.x;
    const int w = t >> 6, l = t & 63, c = l & 15, g = l >> 4;

    f32x4 acc;
    acc[0] = 0.f; acc[1] = 0.f; acc[2] = 0.f; acc[3] = 0.f;

    for (int step = 0; step < 3; ++step) {
        const int kc = ksl * 3 + step;
        const int tensor = kc >> 2;
        const float* src = (tensor == 0) ? q : (tensor == 1) ? k : v;
        src += ((size_t)b * 64) * 1024 + (kc & 3) * 256;
        {
            const int row = t >> 2, seg = t & 3;
            const float* rp = src + row * 1024;
            #pragma unroll
            for (int e = 0; e < 16; ++e) {
                const int col = e * 16 + seg * 4;
                const float4 x = *reinterpret_cast<const float4*>(rp + col);
                unsigned* dp = reinterpret_cast<unsigned*>(&Xs[row * 264 + col]);
                dp[0] = pk2(x.x, x.y); dp[1] = pk2(x.z, x.w);
            }
        }
        {
            const int o = t >> 4, wseg = t & 15;
            const int p0 = ksl * 768 + step * 256;
            const float* wp = (o < 8 ? igw + o * 3072 : fgw + (o - 8) * 3072) + p0;
            #pragma unroll
            for (int e = 0; e < 4; ++e) {
                const int col = e * 64 + wseg * 4;
                const float4 x = *reinterpret_cast<const float4*>(wp + col);
                unsigned* dp = reinterpret_cast<unsigned*>(&Ws[o * 264 + col]);
                dp[0] = pk2(x.x, x.y); dp[1] = pk2(x.z, x.w);
            }
        }
        __syncthreads();
        #pragma unroll
        for (int kk = 0; kk < 8; ++kk) {
            bf16x8 a  = *reinterpret_cast<const bf16x8*>(&Xs[(16 * w + c) * 264 + 32 * kk + 8 * g]);
            bf16x8 bw = *reinterpret_cast<const bf16x8*>(&Ws[c * 264 + 32 * kk + 8 * g]);
            acc = __builtin_amdgcn_mfma_f32_16x16x32_bf16(a, bw, acc, 0, 0, 0);
        }
        __syncthreads();
    }
    float* pb = part + (((size_t)ksl * 256 + b) * 64) * 16;
    #pragma unroll
    for (int reg = 0; reg < 4; ++reg) {
        const int s = 16 * w + 4 * g + reg;
        pb[s * 16 + c] = acc[reg];
    }
}

// ---------------------------------------------------------------------------
// Kernel 1b (r6-PROVEN): reduce partials + bias, log-sigmoid, cumsum, pmax.
// ---------------------------------------------------------------------------
__global__ __launch_bounds__(256) void k_gates_final(
    const float* __restrict__ part, const float* __restrict__ igb, const float* __restrict__ fgb,
    float* __restrict__ ig_ws, float* __restrict__ csum_ws, float* __restrict__ pmax_ws)
{
    const int b = blockIdx.x;
    const int t = threadIdx.x;
    __shared__ float red[64][18];
    {
        const int s = t >> 2, oq = t & 3;
        float4 sum = make_float4(0.f, 0.f, 0.f, 0.f);
        #pragma unroll
        for (int ksl = 0; ksl < 4; ++ksl) {
            const float4 p = *reinterpret_cast<const float4*>(
                part + (((size_t)ksl * 256 + b) * 64 + s) * 16 + oq * 4);
            sum.x += p.x; sum.y += p.y; sum.z += p.z; sum.w += p.w;
        }
        red[s][oq * 4 + 0] = sum.x; red[s][oq * 4 + 1] = sum.y;
        red[s][oq * 4 + 2] = sum.z; red[s][oq * 4 + 3] = sum.w;
    }
    __syncthreads();
    if (t < 64) {
        const int s = t;
        #pragma unroll
        for (int h = 0; h < 8; ++h) {
            float ig = red[s][h]     + igb[h];
            float fg = red[s][8 + h] + fgb[h];
            float lf = logsigf(fg);
            float cs = lf;
            #pragma unroll
            for (int d = 1; d < 64; d <<= 1) {
                float o = __shfl_up(cs, (unsigned)d, 64);
                if (s >= d) cs += o;
            }
            float pm = ig - cs;
            #pragma unroll
            for (int d = 1; d < 64; d <<= 1) {
                float o = __shfl_up(pm, (unsigned)d, 64);
                if (s >= d) pm = fmaxf(pm, o);
            }
            const int base = b * NHH + h;
            ig_ws[base * SS + s] = ig;
            csum_ws[base * 65 + s + 1] = cs;
            if (s == 0) csum_ws[base * 65] = 0.0f;
            pmax_ws[base * SS + s] = pm;
        }
    }
}

// ---------------------------------------------------------------------------
// Kernel 2 (NEW): khop via split-precision MFMA. Block (v,h), 256 threads.
// M=256 batches, N=(v+1) m-values, K=128. PE gathered + hi/lo split in LDS
// (r9-proven [64][136] addressing); q A-frags lane-exact from global with
// register split (r9-proven pattern); D layout gate-proven. Tiles with
// 16n > v skipped: m>v entries are garbage, but attn zeroes j>i before use.
// ---------------------------------------------------------------------------
__global__ __launch_bounds__(256) void k_khop(
    const float* __restrict__ q, const float* __restrict__ rpe, const int* __restrict__ hops,
    float* __restrict__ khop_ws)
{
    __shared__ unsigned short Phi[64 * 136];
    __shared__ unsigned short Plo[64 * 136];
    const int v = blockIdx.x;
    const int h = blockIdx.y;
    const int t = threadIdx.x;
    const int w = t >> 6, l = t & 63, c = l & 15, g = l >> 4;

    // ---- gather PE rows 0..v and split hi/lo ----
    const int nelem = (v + 1) * 128;
    for (int idx = t; idx < nelem; idx += 256) {
        const int m = idx >> 7, cc = idx & 127;
        const float x = rpe[(size_t)hops[v * SS + m] * DIMM + h * DHH + cc];
        const unsigned hi = f2bf(x);
        Phi[m * 136 + cc] = (unsigned short)hi;
        Plo[m * 136 + cc] = (unsigned short)f2bf(x - bf2f((unsigned short)hi));
    }
    __syncthreads();

    const int ntiles = (v >> 4) + 1;
    union bfu { unsigned u[4]; bf16x8 vv; };
    #pragma unroll
    for (int ms = 0; ms < 4; ++ms) {
        const int brow = 64 * w + 16 * ms + c;
        const float* qbase = q + ((size_t)brow * SS + v) * DIMM + h * DHH + 8 * g;
        bfu qhi[4], qlo[4];
        #pragma unroll
        for (int kk = 0; kk < 4; ++kk) {
            const float4 f0 = *reinterpret_cast<const float4*>(qbase + 32 * kk);
            const float4 f1 = *reinterpret_cast<const float4*>(qbase + 32 * kk + 4);
            split2(f0.x, f0.y, qhi[kk].u[0], qlo[kk].u[0]);
            split2(f0.z, f0.w, qhi[kk].u[1], qlo[kk].u[1]);
            split2(f1.x, f1.y, qhi[kk].u[2], qlo[kk].u[2]);
            split2(f1.z, f1.w, qhi[kk].u[3], qlo[kk].u[3]);
        }
        for (int n = 0; n < ntiles; ++n) {       // wave-uniform bound
            f32x4 acc;
            acc[0] = 0.f; acc[1] = 0.f; acc[2] = 0.f; acc[3] = 0.f;
            #pragma unroll
            for (int kk = 0; kk < 4; ++kk) {
                const int off = (16 * n + c) * 136 + 32 * kk + 8 * g;
                bf16x8 bhi = *reinterpret_cast<const bf16x8*>(&Phi[off]);
                bf16x8 blo = *reinterpret_cast<const bf16x8*>(&Plo[off]);
                acc = __builtin_amdgcn_mfma_f32_16x16x32_bf16(qhi[kk].vv, bhi, acc, 0, 0, 0);
                acc = __builtin_amdgcn_mfma_f32_16x16x32_bf16(qlo[kk].vv, bhi, acc, 0, 0, 0);
                acc = __builtin_amdgcn_mfma_f32_16x16x32_bf16(qhi[kk].vv, blo, acc, 0, 0, 0);
            }
            #pragma unroll
            for (int reg = 0; reg < 4; ++reg) {
                const int bo = 64 * w + 16 * ms + 4 * g + reg;   // D row -> batch
                khop_ws[(((size_t)bo * NHH + h) * SS + v) * SS + 16 * n + c] = acc[reg];
            }
        }
    }
}

// ---------------------------------------------------------------------------
// Kernel 3 (r10-PROVEN): split-precision MFMA QK^T + f32 C-phase + bf16 Cn
// + V^T-swizzled MFMA PV + in-register LayerNorm.
// ---------------------------------------------------------------------------
__global__ __launch_bounds__(256) void k_attn(
    const float* __restrict__ q, const float* __restrict__ k, const float* __restrict__ v,
    const float* __restrict__ lnw, const float* __restrict__ lnb,
    const float* __restrict__ ig_ws, const float* __restrict__ csum_ws,
    const float* __restrict__ pmax_ws, const float* __restrict__ khop_ws,
    float* __restrict__ out)
{
    __shared__ __attribute__((aligned(16))) unsigned short Kspl[2 * 64 * 136]; // Khi|Klo -> VT+Cn
    __shared__ float cs[SS][68];        // khop preload -> S+khop -> C
    __shared__ float csum_s[65];
    __shared__ float ig_s[64];
    __shared__ float pmax_s[64];
    __shared__ float invr[64];
    __shared__ float lnw_s[128];
    __shared__ float lnb_s[128];

    const int bid = blockIdx.x;
    const int b = bid >> 3, h = bid & 7;
    const int t = threadIdx.x;
    const int w = t >> 6, l = t & 63, c = l & 15, g = l >> 4;
    const float rs_dh = 0.08838834764831845f;  // 1/sqrt(128)

    unsigned short* Khi = Kspl;               // [64][136]
    unsigned short* Klo = Kspl + 64 * 136;    // [64][136]

    // ---- issue V loads into registers early (written to VT after QK^T) ----
    float4 vreg[2][4];
    #pragma unroll
    for (int it = 0; it < 2; ++it) {
        const int u = t + 256 * it;
        const int jp = u >> 4, seg8 = u & 15;
        const float* r0 = v + ((size_t)(b * 64 + 2 * jp)) * 1024 + h * 128 + seg8 * 8;
        vreg[it][0] = *reinterpret_cast<const float4*>(r0);
        vreg[it][1] = *reinterpret_cast<const float4*>(r0 + 4);
        vreg[it][2] = *reinterpret_cast<const float4*>(r0 + 1024);
        vreg[it][3] = *reinterpret_cast<const float4*>(r0 + 1028);
    }

    // ---- stage K as hi/lo split bf16 (scaled by 1/sqrt(DH) BEFORE split) ----
    #pragma unroll
    for (int it = 0; it < 2; ++it) {
        const int u = t + 256 * it;
        const int row = u >> 3, seg = u & 7;
        const float* kp = k + ((size_t)(b * 64 + row)) * 1024 + h * 128;
        #pragma unroll
        for (int e = 0; e < 2; ++e) {
            const int col = e * 64 + seg * 8;
            const float4 ya = *reinterpret_cast<const float4*>(kp + col);
            const float4 yb = *reinterpret_cast<const float4*>(kp + col + 4);
            unsigned* dh = reinterpret_cast<unsigned*>(&Khi[row * 136 + col]);
            unsigned* dl = reinterpret_cast<unsigned*>(&Klo[row * 136 + col]);
            split2(ya.x * rs_dh, ya.y * rs_dh, dh[0], dl[0]);
            split2(ya.z * rs_dh, ya.w * rs_dh, dh[1], dl[1]);
            split2(yb.x * rs_dh, yb.y * rs_dh, dh[2], dl[2]);
            split2(yb.z * rs_dh, yb.w * rs_dh, dh[3], dl[3]);
        }
    }
    // ---- stage khop f32 into cs (r2-proven pattern) ----
    {
        const float* khb = khop_ws + (b * NHH + h) * SS * SS;
        for (int idx = t; idx < SS * 16; idx += 256) {
            const int row = idx >> 4, j4 = idx & 15;
            *reinterpret_cast<float4*>(&cs[row][j4 * 4]) =
                *reinterpret_cast<const float4*>(khb + row * SS + j4 * 4);
        }
    }
    const int cb = b * NHH + h;
    if (t < 65) csum_s[t] = csum_ws[cb * 65 + t];
    if (t >= 128 && t < 192) ig_s[t - 128] = ig_ws[cb * SS + (t - 128)];
    if (t >= 192) pmax_s[t - 192] = pmax_ws[cb * SS + (t - 192)];
    if (t < 128) lnw_s[t] = lnw[h * 128 + t];
    else if (t < 256) lnb_s[t - 128] = lnb[h * 128 + (t - 128)];

    // ---- Q A-frags from global, split hi/lo in registers (lane-exact reads) ----
    union bfu { unsigned u[4]; bf16x8 v; };
    bfu qhi[4], qlo[4];
    {
        const int qrow = 16 * w + c;
        const float* qbase = q + ((size_t)(b * 64 + qrow)) * 1024 + h * 128 + 8 * g;
        #pragma unroll
        for (int kk = 0; kk < 4; ++kk) {
            const float4 f0 = *reinterpret_cast<const float4*>(qbase + 32 * kk);
            const float4 f1 = *reinterpret_cast<const float4*>(qbase + 32 * kk + 4);
            split2(f0.x, f0.y, qhi[kk].u[0], qlo[kk].u[0]);
            split2(f0.z, f0.w, qhi[kk].u[1], qlo[kk].u[1]);
            split2(f1.x, f1.y, qhi[kk].u[2], qlo[kk].u[2]);
            split2(f1.z, f1.w, qhi[kk].u[3], qlo[kk].u[3]);
        }
    }
    __syncthreads();

    // ---- QK^T via 3-pass split MFMA: S = Qhi*Khi + Qlo*Khi + Qhi*Klo ----
    {
        f32x4 acc[4];
        #pragma unroll
        for (int n = 0; n < 4; ++n) { acc[n][0]=0.f; acc[n][1]=0.f; acc[n][2]=0.f; acc[n][3]=0.f; }
        #pragma unroll
        for (int kk = 0; kk < 4; ++kk) {
            #pragma unroll
            for (int n = 0; n < 4; ++n) {
                const int off = (16 * n + c) * 136 + 32 * kk + 8 * g;
                bf16x8 bhi = *reinterpret_cast<const bf16x8*>(&Khi[off]);
                bf16x8 blo = *reinterpret_cast<const bf16x8*>(&Klo[off]);
                acc[n] = __builtin_amdgcn_mfma_f32_16x16x32_bf16(qhi[kk].v, bhi, acc[n], 0, 0, 0);
                acc[n] = __builtin_amdgcn_mfma_f32_16x16x32_bf16(qlo[kk].v, bhi, acc[n], 0, 0, 0);
                acc[n] = __builtin_amdgcn_mfma_f32_16x16x32_bf16(qhi[kk].v, blo, acc[n], 0, 0, 0);
            }
        }
        #pragma unroll
        for (int n = 0; n < 4; ++n) {
            const int j = 16 * n + c;
            #pragma unroll
            for (int reg = 0; reg < 4; ++reg) {
                const int i = 16 * w + 4 * g + reg;
                cs[i][j] += acc[n][reg];
            }
        }
    }
    __syncthreads();   // Khi/Klo now dead; S complete in cs

    // ---- write V^T (bf16, XOR-swizzled) into dead K region ----
    unsigned short* VT = Kspl;                 // [128 rows][72 shorts] region, swizzled bytes
    unsigned short* Cn = Kspl + 128 * 72;      // [64][72] bf16
    #pragma unroll
    for (int it = 0; it < 2; ++it) {
        const int u = t + 256 * it;
        const int jp = u >> 4, seg8 = u & 15;
        float v0[8], v1[8];
        v0[0]=vreg[it][0].x; v0[1]=vreg[it][0].y; v0[2]=vreg[it][0].z; v0[3]=vreg[it][0].w;
        v0[4]=vreg[it][1].x; v0[5]=vreg[it][1].y; v0[6]=vreg[it][1].z; v0[7]=vreg[it][1].w;
        v1[0]=vreg[it][2].x; v1[1]=vreg[it][2].y; v1[2]=vreg[it][2].z; v1[3]=vreg[it][2].w;
        v1[4]=vreg[it][3].x; v1[5]=vreg[it][3].y; v1[6]=vreg[it][3].z; v1[7]=vreg[it][3].w;
        #pragma unroll
        for (int m = 0; m < 8; ++m) {
            const int cc = seg8 * 8 + m;
            unsigned byte = (unsigned)(cc * 144 + 4 * jp);
            byte ^= ((cc >> 3) & 7) << 4;
            *reinterpret_cast<unsigned*>(reinterpret_cast<char*>(VT) + byte) = pk2(v0[m], v1[m]);
        }
    }

    // ---- C phase (r9-proven formulas) ----
    const int i = t >> 2, qq = t & 3;
    {
        const float m_i = csum_s[i + 1] + pmax_s[i];
        float rs = 0.0f;
        for (int j = qq; j <= i; j += 4) {
            const float sc = cs[i][j];
            const float logD = csum_s[i + 1] - csum_s[j + 1] + ig_s[j];
            const float C = sc * __expf(logD - m_i);
            rs += C;
            cs[i][j] = C;
        }
        for (int j = i + 1 + ((qq - (i + 1)) & 3); j < SS; j += 4) cs[i][j] = 0.0f;
        rs += __shfl_xor(rs, 1, 64);
        rs += __shfl_xor(rs, 2, 64);
        const float nrm = fmaxf(fabsf(rs), __expf(-m_i));
        if (qq == 0) invr[i] = 1.0f / (nrm + 1e-6f);
    }
    __syncthreads();

    // ---- convert C -> bf16 Cn (x invr) ----
    {
        const int row = t >> 2, qtr = t & 3;
        const float ir = invr[row];
        unsigned* dp = reinterpret_cast<unsigned*>(&Cn[row * 72 + qtr * 16]);
        #pragma unroll
        for (int e = 0; e < 4; ++e) {
            const float4 x = *reinterpret_cast<const float4*>(&cs[row][qtr * 16 + e * 4]);
            dp[e * 2 + 0] = pk2(x.x * ir, x.y * ir);
            dp[e * 2 + 1] = pk2(x.z * ir, x.w * ir);
        }
    }
    __syncthreads();

    // ---- PV via MFMA: H[16-row strip][128] per wave ----
    f32x4 hacc[8];
    #pragma unroll
    for (int n = 0; n < 8; ++n) { hacc[n][0]=0.f; hacc[n][1]=0.f; hacc[n][2]=0.f; hacc[n][3]=0.f; }
    #pragma unroll
    for (int ks = 0; ks < 2; ++ks) {
        bf16x8 a = *reinterpret_cast<const bf16x8*>(&Cn[(16 * w + c) * 72 + 32 * ks + 8 * g]);
        #pragma unroll
        for (int n = 0; n < 8; ++n) {
            const int cc = 16 * n + c;
            unsigned byte = (unsigned)(cc * 144 + 64 * ks + 16 * g);
            byte ^= ((cc >> 3) & 7) << 4;
            bf16x8 bv = *reinterpret_cast<const bf16x8*>(reinterpret_cast<const char*>(VT) + byte);
            hacc[n] = __builtin_amdgcn_mfma_f32_16x16x32_bf16(a, bv, hacc[n], 0, 0, 0);
        }
    }

    // ---- fused per-head LayerNorm + output (in fragment registers) ----
    #pragma unroll
    for (int reg = 0; reg < 4; ++reg) {
        float s1 = 0.f, s2 = 0.f;
        #pragma unroll
        for (int n = 0; n < 8; ++n) { const float x = hacc[n][reg]; s1 += x; s2 = fmaf(x, x, s2); }
        s1 += __shfl_xor(s1, 1); s1 += __shfl_xor(s1, 2);
        s1 += __shfl_xor(s1, 4); s1 += __shfl_xor(s1, 8);
        s2 += __shfl_xor(s2, 1); s2 += __shfl_xor(s2, 2);
        s2 += __shfl_xor(s2, 4); s2 += __shfl_xor(s2, 8);
        const float mu = s1 * (1.0f / 128.0f);
        const float var = s2 * (1.0f / 128.0f) - mu * mu;
        const float rstd = rsqrtf(var + 1e-5f);
        const int io = 16 * w + 4 * g + reg;
        float* op = out + (((size_t)(b * 64 + io)) * 8 + h) * 128;
        #pragma unroll
        for (int n = 0; n < 8; ++n) {
            const int cc = 16 * n + c;
            op[cc] = (hacc[n][reg] - mu) * rstd * (1.0f + lnw_s[cc]) + lnb_s[cc];
        }
    }
}

extern "C" void kernel_launch(void* const* d_in, const int* in_sizes, int n_in,
                              void* d_out, int out_size, void* d_ws, size_t ws_size,
                              hipStream_t stream) {
    const float* q   = (const float*)d_in[0];
    const float* k   = (const float*)d_in[1];
    const float* v   = (const float*)d_in[2];
    const float* igw = (const float*)d_in[3];
    const float* igb = (const float*)d_in[4];
    const float* fgw = (const float*)d_in[5];
    const float* fgb = (const float*)d_in[6];
    const float* rpe = (const float*)d_in[7];
    const float* lnw = (const float*)d_in[8];
    const float* lnb = (const float*)d_in[9];
    const int*  hops = (const int*)d_in[10];
    float* out = (float*)d_out;

    // ws (floats): ig[131072] | pmax[131072] | csum[133120] | REGION (aliased):
    //   gate-MFMA partials (1.05M f32) consumed by k_gates_final BEFORE k_khop
    //   overwrites the region as khop_ws (8.39M f32). Same-stream ordering.
    float* ig_ws   = (float*)d_ws;
    float* pmax_ws = ig_ws + 131072;
    float* csum_ws = pmax_ws + 131072;
    float* part    = csum_ws + 133120;
    float* khop_ws = part;

    hipLaunchKernelGGL(k_gate_mfma, dim3(1024), dim3(256), 0, stream,
                       q, k, v, igw, fgw, part);
    hipLaunchKernelGGL(k_gates_final, dim3(BB), dim3(256), 0, stream,
                       part, igb, fgb, ig_ws, csum_ws, pmax_ws);
    hipLaunchKernelGGL(k_khop, dim3(SS, NHH), dim3(256), 0, stream,
                       q, rpe, hops, khop_ws);
    hipLaunchKernelGGL(k_attn, dim3(BB * NHH), dim3(256), 0, stream,
                       q, k, v, lnw, lnb, ig_ws, csum_ws, pmax_ws, khop_ws, out);
}

// Round 12
// 129.033 us; speedup vs baseline: 4.4239x; 1.0462x over previous
//
#include <hip/hip_runtime.h>
#include <math.h>

#define BB 256
#define SS 64
#define DIMM 1024
#define NHH 8
#define DHH 128

typedef short bf16x8 __attribute__((ext_vector_type(8)));
typedef float f32x4 __attribute__((ext_vector_type(4)));

__device__ __forceinline__ unsigned f2bf(float f) {   // bf16 bits (RNE) in low 16
    union { float f; unsigned u; } x{f};
    return (x.u + 0x7FFFu + ((x.u >> 16) & 1u)) >> 16;
}
__device__ __forceinline__ unsigned pk2(float lo, float hi) {
    return f2bf(lo) | (f2bf(hi) << 16);
}
__device__ __forceinline__ float bf2f(unsigned short b) {
    union { unsigned u; float f; } x{((unsigned)b) << 16};
    return x.f;
}
// split a,b into hi-bf16 pair and residual-lo-bf16 pair (packed words)
__device__ __forceinline__ void split2(float a, float b, unsigned& hi, unsigned& lo) {
    const unsigned ha = f2bf(a), hb = f2bf(b);
    hi = ha | (hb << 16);
    lo = pk2(a - bf2f((unsigned short)ha), b - bf2f((unsigned short)hb));
}
__device__ __forceinline__ float logsigf(float x) {
    return fminf(x, 0.0f) - log1pf(__expf(-fabsf(x)));
}

// ---------------------------------------------------------------------------
// Kernel 1a (r6-PROVEN): gate GEMM partials via MFMA.
// ---------------------------------------------------------------------------
__global__ __launch_bounds__(256) void k_gate_mfma(
    const float* __restrict__ q, const float* __restrict__ k, const float* __restrict__ v,
    const float* __restrict__ igw, const float* __restrict__ fgw,
    float* __restrict__ part)
{
    __shared__ unsigned short Xs[64 * 264];   // [64][256+8] bf16
    __shared__ unsigned short Ws[16 * 264];
    const int b = blockIdx.x & 255;
    const int ksl = blockIdx.x >> 8;
    const int t = threadIdx.x;
    const int w = t >> 6, l = t & 63, c = l & 15, g = l >> 4;

    f32x4 acc;
    acc[0] = 0.f; acc[1] = 0.f; acc[2] = 0.f; acc[3] = 0.f;

    for (int step = 0; step < 3; ++step) {
        const int kc = ksl * 3 + step;
        const int tensor = kc >> 2;
        const float* src = (tensor == 0) ? q : (tensor == 1) ? k : v;
        src += ((size_t)b * 64) * 1024 + (kc & 3) * 256;
        {
            const int row = t >> 2, seg = t & 3;
            const float* rp = src + row * 1024;
            #pragma unroll
            for (int e = 0; e < 16; ++e) {
                const int col = e * 16 + seg * 4;
                const float4 x = *reinterpret_cast<const float4*>(rp + col);
                unsigned* dp = reinterpret_cast<unsigned*>(&Xs[row * 264 + col]);
                dp[0] = pk2(x.x, x.y); dp[1] = pk2(x.z, x.w);
            }
        }
        {
            const int o = t >> 4, wseg = t & 15;
            const int p0 = ksl * 768 + step * 256;
            const float* wp = (o < 8 ? igw + o * 3072 : fgw + (o - 8) * 3072) + p0;
            #pragma unroll
            for (int e = 0; e < 4; ++e) {
                const int col = e * 64 + wseg * 4;
                const float4 x = *reinterpret_cast<const float4*>(wp + col);
                unsigned* dp = reinterpret_cast<unsigned*>(&Ws[o * 264 + col]);
                dp[0] = pk2(x.x, x.y); dp[1] = pk2(x.z, x.w);
            }
        }
        __syncthreads();
        #pragma unroll
        for (int kk = 0; kk < 8; ++kk) {
            bf16x8 a  = *reinterpret_cast<const bf16x8*>(&Xs[(16 * w + c) * 264 + 32 * kk + 8 * g]);
            bf16x8 bw = *reinterpret_cast<const bf16x8*>(&Ws[c * 264 + 32 * kk + 8 * g]);
            acc = __builtin_amdgcn_mfma_f32_16x16x32_bf16(a, bw, acc, 0, 0, 0);
        }
        __syncthreads();
    }
    float* pb = part + (((size_t)ksl * 256 + b) * 64) * 16;
    #pragma unroll
    for (int reg = 0; reg < 4; ++reg) {
        const int s = 16 * w + 4 * g + reg;
        pb[s * 16 + c] = acc[reg];
    }
}

// ---------------------------------------------------------------------------
// Kernel 1b (r6-PROVEN): reduce partials + bias, log-sigmoid, cumsum, pmax.
// ---------------------------------------------------------------------------
__global__ __launch_bounds__(256) void k_gates_final(
    const float* __restrict__ part, const float* __restrict__ igb, const float* __restrict__ fgb,
    float* __restrict__ ig_ws, float* __restrict__ csum_ws, float* __restrict__ pmax_ws)
{
    const int b = blockIdx.x;
    const int t = threadIdx.x;
    __shared__ float red[64][18];
    {
        const int s = t >> 2, oq = t & 3;
        float4 sum = make_float4(0.f, 0.f, 0.f, 0.f);
        #pragma unroll
        for (int ksl = 0; ksl < 4; ++ksl) {
            const float4 p = *reinterpret_cast<const float4*>(
                part + (((size_t)ksl * 256 + b) * 64 + s) * 16 + oq * 4);
            sum.x += p.x; sum.y += p.y; sum.z += p.z; sum.w += p.w;
        }
        red[s][oq * 4 + 0] = sum.x; red[s][oq * 4 + 1] = sum.y;
        red[s][oq * 4 + 2] = sum.z; red[s][oq * 4 + 3] = sum.w;
    }
    __syncthreads();
    if (t < 64) {
        const int s = t;
        #pragma unroll
        for (int h = 0; h < 8; ++h) {
            float ig = red[s][h]     + igb[h];
            float fg = red[s][8 + h] + fgb[h];
            float lf = logsigf(fg);
            float cs = lf;
            #pragma unroll
            for (int d = 1; d < 64; d <<= 1) {
                float o = __shfl_up(cs, (unsigned)d, 64);
                if (s >= d) cs += o;
            }
            float pm = ig - cs;
            #pragma unroll
            for (int d = 1; d < 64; d <<= 1) {
                float o = __shfl_up(pm, (unsigned)d, 64);
                if (s >= d) pm = fmaxf(pm, o);
            }
            const int base = b * NHH + h;
            ig_ws[base * SS + s] = ig;
            csum_ws[base * 65 + s + 1] = cs;
            if (s == 0) csum_ws[base * 65] = 0.0f;
            pmax_ws[base * SS + s] = pm;
        }
    }
}

// ---------------------------------------------------------------------------
// Kernel 2 (r11-PROVEN): khop via split-precision MFMA.
// ---------------------------------------------------------------------------
__global__ __launch_bounds__(256) void k_khop(
    const float* __restrict__ q, const float* __restrict__ rpe, const int* __restrict__ hops,
    float* __restrict__ khop_ws)
{
    __shared__ unsigned short Phi[64 * 136];
    __shared__ unsigned short Plo[64 * 136];
    const int v = blockIdx.x;
    const int h = blockIdx.y;
    const int t = threadIdx.x;
    const int w = t >> 6, l = t & 63, c = l & 15, g = l >> 4;

    // ---- gather PE rows 0..v and split hi/lo ----
    const int nelem = (v + 1) * 128;
    for (int idx = t; idx < nelem; idx += 256) {
        const int m = idx >> 7, cc = idx & 127;
        const float x = rpe[(size_t)hops[v * SS + m] * DIMM + h * DHH + cc];
        const unsigned hi = f2bf(x);
        Phi[m * 136 + cc] = (unsigned short)hi;
        Plo[m * 136 + cc] = (unsigned short)f2bf(x - bf2f((unsigned short)hi));
    }
    __syncthreads();

    const int ntiles = (v >> 4) + 1;
    union bfu { unsigned u[4]; bf16x8 vv; };
    #pragma unroll
    for (int ms = 0; ms < 4; ++ms) {
        const int brow = 64 * w + 16 * ms + c;
        const float* qbase = q + ((size_t)brow * SS + v) * DIMM + h * DHH + 8 * g;
        bfu qhi[4], qlo[4];
        #pragma unroll
        for (int kk = 0; kk < 4; ++kk) {
            const float4 f0 = *reinterpret_cast<const float4*>(qbase + 32 * kk);
            const float4 f1 = *reinterpret_cast<const float4*>(qbase + 32 * kk + 4);
            split2(f0.x, f0.y, qhi[kk].u[0], qlo[kk].u[0]);
            split2(f0.z, f0.w, qhi[kk].u[1], qlo[kk].u[1]);
            split2(f1.x, f1.y, qhi[kk].u[2], qlo[kk].u[2]);
            split2(f1.z, f1.w, qhi[kk].u[3], qlo[kk].u[3]);
        }
        for (int n = 0; n < ntiles; ++n) {       // wave-uniform bound
            f32x4 acc;
            acc[0] = 0.f; acc[1] = 0.f; acc[2] = 0.f; acc[3] = 0.f;
            #pragma unroll
            for (int kk = 0; kk < 4; ++kk) {
                const int off = (16 * n + c) * 136 + 32 * kk + 8 * g;
                bf16x8 bhi = *reinterpret_cast<const bf16x8*>(&Phi[off]);
                bf16x8 blo = *reinterpret_cast<const bf16x8*>(&Plo[off]);
                acc = __builtin_amdgcn_mfma_f32_16x16x32_bf16(qhi[kk].vv, bhi, acc, 0, 0, 0);
                acc = __builtin_amdgcn_mfma_f32_16x16x32_bf16(qlo[kk].vv, bhi, acc, 0, 0, 0);
                acc = __builtin_amdgcn_mfma_f32_16x16x32_bf16(qhi[kk].vv, blo, acc, 0, 0, 0);
            }
            #pragma unroll
            for (int reg = 0; reg < 4; ++reg) {
                const int bo = 64 * w + 16 * ms + 4 * g + reg;   // D row -> batch
                khop_ws[(((size_t)bo * NHH + h) * SS + v) * SS + 16 * n + c] = acc[reg];
            }
        }
    }
}

// ---------------------------------------------------------------------------
// Kernel 3: split-QK^T (r11-proven) + khop lane-exact in REGISTERS (D-layout)
// + D-weight/rowsum/normalizer in fragment registers (r7 epilogue, exonerated)
// + bf16 Cn + VT-swizzled MFMA PV + in-register LN (r11-proven).
// cs tile eliminated -> LDS ~36.6 KB -> 4 blocks/CU.
// ---------------------------------------------------------------------------
__global__ __launch_bounds__(256) void k_attn(
    const float* __restrict__ q, const float* __restrict__ k, const float* __restrict__ v,
    const float* __restrict__ lnw, const float* __restrict__ lnb,
    const float* __restrict__ ig_ws, const float* __restrict__ csum_ws,
    const float* __restrict__ pmax_ws, const float* __restrict__ khop_ws,
    float* __restrict__ out)
{
    __shared__ __attribute__((aligned(16))) unsigned short Kspl[2 * 64 * 136]; // Khi|Klo -> VT+Cn
    __shared__ float csum_s[65];
    __shared__ float ig_s[64];
    __shared__ float pmax_s[64];
    __shared__ float lnw_s[128];
    __shared__ float lnb_s[128];

    const int bid = blockIdx.x;
    const int b = bid >> 3, h = bid & 7;
    const int t = threadIdx.x;
    const int w = t >> 6, l = t & 63, c = l & 15, g = l >> 4;
    const float rs_dh = 0.08838834764831845f;  // 1/sqrt(128)

    unsigned short* Khi = Kspl;               // [64][136]
    unsigned short* Klo = Kspl + 64 * 136;    // [64][136]

    // ---- issue V loads into registers early (written to VT after QK^T) ----
    float4 vreg[2][4];
    #pragma unroll
    for (int it = 0; it < 2; ++it) {
        const int u = t + 256 * it;
        const int jp = u >> 4, seg8 = u & 15;
        const float* r0 = v + ((size_t)(b * 64 + 2 * jp)) * 1024 + h * 128 + seg8 * 8;
        vreg[it][0] = *reinterpret_cast<const float4*>(r0);
        vreg[it][1] = *reinterpret_cast<const float4*>(r0 + 4);
        vreg[it][2] = *reinterpret_cast<const float4*>(r0 + 1024);
        vreg[it][3] = *reinterpret_cast<const float4*>(r0 + 1028);
    }

    // ---- khop lane-exact into registers (D-fragment layout [i][j]) ----
    float kh[4][4];
    {
        const float* khb = khop_ws + ((size_t)(b * NHH + h) * SS) * SS;
        #pragma unroll
        for (int n = 0; n < 4; ++n) {
            #pragma unroll
            for (int reg = 0; reg < 4; ++reg) {
                const int i = 16 * w + 4 * g + reg;
                kh[n][reg] = khb[(size_t)i * SS + 16 * n + c];
            }
        }
    }

    // ---- stage K as hi/lo split bf16 (scaled by 1/sqrt(DH) BEFORE split) ----
    #pragma unroll
    for (int it = 0; it < 2; ++it) {
        const int u = t + 256 * it;
        const int row = u >> 3, seg = u & 7;
        const float* kp = k + ((size_t)(b * 64 + row)) * 1024 + h * 128;
        #pragma unroll
        for (int e = 0; e < 2; ++e) {
            const int col = e * 64 + seg * 8;
            const float4 ya = *reinterpret_cast<const float4*>(kp + col);
            const float4 yb = *reinterpret_cast<const float4*>(kp + col + 4);
            unsigned* dh = reinterpret_cast<unsigned*>(&Khi[row * 136 + col]);
            unsigned* dl = reinterpret_cast<unsigned*>(&Klo[row * 136 + col]);
            split2(ya.x * rs_dh, ya.y * rs_dh, dh[0], dl[0]);
            split2(ya.z * rs_dh, ya.w * rs_dh, dh[1], dl[1]);
            split2(yb.x * rs_dh, yb.y * rs_dh, dh[2], dl[2]);
            split2(yb.z * rs_dh, yb.w * rs_dh, dh[3], dl[3]);
        }
    }
    const int cb = b * NHH + h;
    if (t < 65) csum_s[t] = csum_ws[cb * 65 + t];
    if (t >= 128 && t < 192) ig_s[t - 128] = ig_ws[cb * SS + (t - 128)];
    if (t >= 192) pmax_s[t - 192] = pmax_ws[cb * SS + (t - 192)];
    if (t < 128) lnw_s[t] = lnw[h * 128 + t];
    else if (t < 256) lnb_s[t - 128] = lnb[h * 128 + (t - 128)];

    // ---- Q A-frags from global, split hi/lo in registers (lane-exact reads) ----
    union bfu { unsigned u[4]; bf16x8 v; };
    bfu qhi[4], qlo[4];
    {
        const int qrow = 16 * w + c;
        const float* qbase = q + ((size_t)(b * 64 + qrow)) * 1024 + h * 128 + 8 * g;
        #pragma unroll
        for (int kk = 0; kk < 4; ++kk) {
            const float4 f0 = *reinterpret_cast<const float4*>(qbase + 32 * kk);
            const float4 f1 = *reinterpret_cast<const float4*>(qbase + 32 * kk + 4);
            split2(f0.x, f0.y, qhi[kk].u[0], qlo[kk].u[0]);
            split2(f0.z, f0.w, qhi[kk].u[1], qlo[kk].u[1]);
            split2(f1.x, f1.y, qhi[kk].u[2], qlo[kk].u[2]);
            split2(f1.z, f1.w, qhi[kk].u[3], qlo[kk].u[3]);
        }
    }
    __syncthreads();

    // ---- QK^T via 3-pass split MFMA: S = Qhi*Khi + Qlo*Khi + Qhi*Klo ----
    f32x4 acc[4];
    #pragma unroll
    for (int n = 0; n < 4; ++n) { acc[n][0]=0.f; acc[n][1]=0.f; acc[n][2]=0.f; acc[n][3]=0.f; }
    #pragma unroll
    for (int kk = 0; kk < 4; ++kk) {
        #pragma unroll
        for (int n = 0; n < 4; ++n) {
            const int off = (16 * n + c) * 136 + 32 * kk + 8 * g;
            bf16x8 bhi = *reinterpret_cast<const bf16x8*>(&Khi[off]);
            bf16x8 blo = *reinterpret_cast<const bf16x8*>(&Klo[off]);
            acc[n] = __builtin_amdgcn_mfma_f32_16x16x32_bf16(qhi[kk].v, bhi, acc[n], 0, 0, 0);
            acc[n] = __builtin_amdgcn_mfma_f32_16x16x32_bf16(qlo[kk].v, bhi, acc[n], 0, 0, 0);
            acc[n] = __builtin_amdgcn_mfma_f32_16x16x32_bf16(qhi[kk].v, blo, acc[n], 0, 0, 0);
        }
    }
    __syncthreads();   // Khi/Klo now dead

    // ---- write V^T (bf16, XOR-swizzled) into dead K region ----
    unsigned short* VT = Kspl;                 // swizzled-byte region
    unsigned short* Cn = Kspl + 128 * 72;      // [64][72] bf16
    #pragma unroll
    for (int it = 0; it < 2; ++it) {
        const int u = t + 256 * it;
        const int jp = u >> 4, seg8 = u & 15;
        float v0[8], v1[8];
        v0[0]=vreg[it][0].x; v0[1]=vreg[it][0].y; v0[2]=vreg[it][0].z; v0[3]=vreg[it][0].w;
        v0[4]=vreg[it][1].x; v0[5]=vreg[it][1].y; v0[6]=vreg[it][1].z; v0[7]=vreg[it][1].w;
        v1[0]=vreg[it][2].x; v1[1]=vreg[it][2].y; v1[2]=vreg[it][2].z; v1[3]=vreg[it][2].w;
        v1[4]=vreg[it][3].x; v1[5]=vreg[it][3].y; v1[6]=vreg[it][3].z; v1[7]=vreg[it][3].w;
        #pragma unroll
        for (int m = 0; m < 8; ++m) {
            const int cc = seg8 * 8 + m;
            unsigned byte = (unsigned)(cc * 144 + 4 * jp);
            byte ^= ((cc >> 3) & 7) << 4;
            *reinterpret_cast<unsigned*>(reinterpret_cast<char*>(VT) + byte) = pk2(v0[m], v1[m]);
        }
    }

    // ---- D-weight + rowsum + normalizer in fragment registers (r7 epilogue) ----
    {
        float mi[4], rs[4];
        #pragma unroll
        for (int reg = 0; reg < 4; ++reg) {
            const int i = 16 * w + 4 * g + reg;
            mi[reg] = csum_s[i + 1] + pmax_s[i];
            rs[reg] = 0.0f;
        }
        #pragma unroll
        for (int n = 0; n < 4; ++n) {
            const int j = 16 * n + c;
            const float cj = csum_s[j + 1], igj = ig_s[j];
            #pragma unroll
            for (int reg = 0; reg < 4; ++reg) {
                const int i = 16 * w + 4 * g + reg;
                float val = 0.0f;
                if (j <= i) {
                    const float sc = acc[n][reg] + kh[n][reg];
                    val = sc * __expf(csum_s[i + 1] - cj + igj - mi[reg]);
                }
                acc[n][reg] = val;
                rs[reg] += val;
            }
        }
        #pragma unroll
        for (int reg = 0; reg < 4; ++reg) {
            float r = rs[reg];
            r += __shfl_xor(r, 1); r += __shfl_xor(r, 2);
            r += __shfl_xor(r, 4); r += __shfl_xor(r, 8);
            const float nrm = fmaxf(fabsf(r), __expf(-mi[reg]));
            const float inv = 1.0f / (nrm + 1e-6f);
            const int i = 16 * w + 4 * g + reg;
            #pragma unroll
            for (int n = 0; n < 4; ++n) {
                const int j = 16 * n + c;
                Cn[i * 72 + j] = (unsigned short)f2bf(acc[n][reg] * inv);
            }
        }
    }
    __syncthreads();

    // ---- PV via MFMA: H[16-row strip][128] per wave ----
    f32x4 hacc[8];
    #pragma unroll
    for (int n = 0; n < 8; ++n) { hacc[n][0]=0.f; hacc[n][1]=0.f; hacc[n][2]=0.f; hacc[n][3]=0.f; }
    #pragma unroll
    for (int ks = 0; ks < 2; ++ks) {
        bf16x8 a = *reinterpret_cast<const bf16x8*>(&Cn[(16 * w + c) * 72 + 32 * ks + 8 * g]);
        #pragma unroll
        for (int n = 0; n < 8; ++n) {
            const int cc = 16 * n + c;
            unsigned byte = (unsigned)(cc * 144 + 64 * ks + 16 * g);
            byte ^= ((cc >> 3) & 7) << 4;
            bf16x8 bv = *reinterpret_cast<const bf16x8*>(reinterpret_cast<const char*>(VT) + byte);
            hacc[n] = __builtin_amdgcn_mfma_f32_16x16x32_bf16(a, bv, hacc[n], 0, 0, 0);
        }
    }

    // ---- fused per-head LayerNorm + output (in fragment registers) ----
    #pragma unroll
    for (int reg = 0; reg < 4; ++reg) {
        float s1 = 0.f, s2 = 0.f;
        #pragma unroll
        for (int n = 0; n < 8; ++n) { const float x = hacc[n][reg]; s1 += x; s2 = fmaf(x, x, s2); }
        s1 += __shfl_xor(s1, 1); s1 += __shfl_xor(s1, 2);
        s1 += __shfl_xor(s1, 4); s1 += __shfl_xor(s1, 8);
        s2 += __shfl_xor(s2, 1); s2 += __shfl_xor(s2, 2);
        s2 += __shfl_xor(s2, 4); s2 += __shfl_xor(s2, 8);
        const float mu = s1 * (1.0f / 128.0f);
        const float var = s2 * (1.0f / 128.0f) - mu * mu;
        const float rstd = rsqrtf(var + 1e-5f);
        const int io = 16 * w + 4 * g + reg;
        float* op = out + (((size_t)(b * 64 + io)) * 8 + h) * 128;
        #pragma unroll
        for (int n = 0; n < 8; ++n) {
            const int cc = 16 * n + c;
            op[cc] = (hacc[n][reg] - mu) * rstd * (1.0f + lnw_s[cc]) + lnb_s[cc];
        }
    }
}

extern "C" void kernel_launch(void* const* d_in, const int* in_sizes, int n_in,
                              void* d_out, int out_size, void* d_ws, size_t ws_size,
                              hipStream_t stream) {
    const float* q   = (const float*)d_in[0];
    const float* k   = (const float*)d_in[1];
    const float* v   = (const float*)d_in[2];
    const float* igw = (const float*)d_in[3];
    const float* igb = (const float*)d_in[4];
    const float* fgw = (const float*)d_in[5];
    const float* fgb = (const float*)d_in[6];
    const float* rpe = (const float*)d_in[7];
    const float* lnw = (const float*)d_in[8];
    const float* lnb = (const float*)d_in[9];
    const int*  hops = (const int*)d_in[10];
    float* out = (float*)d_out;

    // ws (floats): ig[131072] | pmax[131072] | csum[133120] | REGION (aliased):
    //   gate-MFMA partials (1.05M f32) consumed by k_gates_final BEFORE k_khop
    //   overwrites the region as khop_ws (8.39M f32). Same-stream ordering.
    float* ig_ws   = (float*)d_ws;
    float* pmax_ws = ig_ws + 131072;
    float* csum_ws = pmax_ws + 131072;
    float* part    = csum_ws + 133120;
    float* khop_ws = part;

    hipLaunchKernelGGL(k_gate_mfma, dim3(1024), dim3(256), 0, stream,
                       q, k, v, igw, fgw, part);
    hipLaunchKernelGGL(k_gates_final, dim3(BB), dim3(256), 0, stream,
                       part, igb, fgb, ig_ws, csum_ws, pmax_ws);
    hipLaunchKernelGGL(k_khop, dim3(SS, NHH), dim3(256), 0, stream,
                       q, rpe, hops, khop_ws);
    hipLaunchKernelGGL(k_attn, dim3(BB * NHH), dim3(256), 0, stream,
                       q, k, v, lnw, lnb, ig_ws, csum_ws, pmax_ws, khop_ws, out);
}